// Round 7
// baseline (386.149 us; speedup 1.0000x reference)
//
#include <hip/hip_runtime.h>
#include <math.h>

#pragma clang fp contract(off)

#define MPTS   2097152
#define NIMG   16
#define NCLS   11
#define CUTB   0x3F000000u   /* __float_as_uint(0.5f) — histogram floor */
#define NB2    1026          /* bins covering s in [0.5, 1.0] (+guard) */
#define NB2P   1040          /* padded per-image stride */
#define MARG   96u
#define CAP    4096
#define SORTN  4096
#define TOPN   1000
#define OUTN   100
#define LCAP   64            /* per-block per-image LDS candidate slots */

typedef unsigned long long u64;

// triangular suppression-mask storage: per image, chunks c=0..15 (rows 64c..64c+63),
// each row stores words w=c..15 (j-words); chunk base in u64 words:
#define SUPW_PER_IMG 8704
__device__ __forceinline__ int chunk_base(int c) {
    return 64 * (16 * c - (c * (c - 1)) / 2);
}

// exact f32 sigmoid mirroring numpy: e = f32(exp64(-x)); 1/(1+e) in f32
__device__ inline float sigx(float x) {
    float e = (float)exp(-(double)x);
    return 1.0f / (1.0f + e);
}
// fast screen-only sigmoid (v_exp + v_rcp, ~2-3 ulp; margins are >=96 codes)
__device__ inline float sigf(float x) {
    float e = __expf(-x);
    return __builtin_amdgcn_rcpf(1.0f + e);
}
// round f32 -> bf16 (RNE) -> f32, to match the bf16-quantized reference
__device__ inline float bfr(float x) {
    unsigned u = __float_as_uint(x);
    unsigned r = (u + 0x7FFFu + ((u >> 16) & 1u)) & 0xFFFF0000u;
    return __uint_as_float(r);
}

// ---- pass A: per-image FAST histogram of score bits, range [0.5, 1.0] ---
__global__ __launch_bounds__(1024)
void k_hist(const float4* __restrict__ cls4, const float* __restrict__ ctr,
            const int* __restrict__ batch, unsigned* __restrict__ ghist) {
    __shared__ unsigned hist[NB2];
    __shared__ int simg;
    const int F4  = MPTS * NCLS / 4;       // 5767168 float4s
    const int FPB = F4 / 512;              // 11264 per block
    int f0 = blockIdx.x * FPB;
    int t = threadIdx.x;
    for (int i = t; i < NB2; i += 1024) hist[i] = 0;
    if (t == 0) simg = batch[(unsigned)(4u * (unsigned)f0) / NCLS];
    __syncthreads();
    int bi = simg;
    unsigned pc = 0xFFFFFFFFu;             // cached point
    float sfc = 0.0f;
    int bc = 0;
    for (int f = f0 + t; f < f0 + FPB; f += 1024) {
        float4 v = cls4[f];
        float va[4] = {v.x, v.y, v.z, v.w};
        unsigned e0 = 4u * (unsigned)f;
        #pragma unroll
        for (int j = 0; j < 4; j++) {
            float ck = va[j];
            if (ck <= 0.0f) continue;      // s <= 0.5: below histogram range
            unsigned e = e0 + (unsigned)j;
            unsigned p = e / NCLS;
            unsigned k = e - p * NCLS;
            if (k == 10u) continue;        // class 10 zeroed by ref
            if (p != pc) {
                pc = p; sfc = sigf(ctr[p]); bc = batch[p];
            }
            unsigned fb = __float_as_uint(sigf(ck) * sfc);
            if (fb < CUTB) continue;
            unsigned bin = (fb - CUTB) >> 13;
            if (bin >= NB2) bin = NB2 - 1;             // s==1.0 guard
            if (bc == bi) atomicAdd(&hist[bin], 1u);
            else          atomicAdd(&ghist[(size_t)bc * NB2P + bin], 1u);
        }
    }
    __syncthreads();
    unsigned* gh = ghist + (size_t)bi * NB2P;
    for (int i = t; i < NB2; i += 1024) {
        unsigned v2 = hist[i];
        if (v2) atomicAdd(&gh[i], v2);
    }
}

// ---- threshold: largest bin B with fast-suffix-count >= TOPN -----------
__global__ void k_thresh(const unsigned* __restrict__ ghist, unsigned* __restrict__ thrbuf) {
    int img = blockIdx.x;
    const unsigned* h = ghist + (size_t)img * NB2P;
    __shared__ unsigned psum[256];
    int t = threadIdx.x;
    unsigned s = 0;
    int base = t * 5;                      // 5 bins/thread, threads 0..205 cover 1026
    for (int i = 0; i < 5; i++) { int b = base + i; if (b < NB2) s += h[b]; }
    psum[t] = s;
    __syncthreads();
    if (t == 0) {
        unsigned run = 0; int B = 0;
        for (int u = 205; u >= 0; u--) {
            if (run + psum[u] >= (unsigned)TOPN) {
                int btop = u * 5 + 4; if (btop > NB2 - 1) btop = NB2 - 1;
                for (int b = btop; b >= u * 5; b--) {
                    run += h[b];
                    if (run >= (unsigned)TOPN) { B = b; break; }
                }
                break;
            }
            run += psum[u];
        }
        unsigned TB = CUTB + ((unsigned)B << 13) - MARG;   // fast->exact slack
        thrbuf[2 * img] = TB;
        thrbuf[2 * img + 1] = __float_as_uint(__uint_as_float(TB) * 0.998f); // screen
    }
}

// ---- pass B: collect u64 keys, LDS-staged (privatized counters) --------
__global__ __launch_bounds__(256)
void k_collect(const float4* __restrict__ cls4, const float* __restrict__ ctr,
               const int* __restrict__ batch, const unsigned* __restrict__ thrbuf,
               unsigned* __restrict__ gcnt, unsigned long long* __restrict__ cand) {
    __shared__ unsigned sTB[NIMG];
    __shared__ float sSCR[NIMG];
    __shared__ u64 lbuf[NIMG][LCAP];
    __shared__ unsigned lcnt[NIMG];
    __shared__ unsigned lbase[NIMG];
    int t = threadIdx.x;
    if (t < NIMG) {
        sTB[t]  = thrbuf[2 * t];
        sSCR[t] = __uint_as_float(thrbuf[2 * t + 1]);
        lcnt[t] = 0;
    }
    __syncthreads();
    const int F4  = MPTS * NCLS / 4;       // 5767168
    const int FPB = F4 / 2048;             // 2816 per block
    int f0 = blockIdx.x * FPB;
    unsigned pc = 0xFFFFFFFFu;
    float cgs = 0.0f, sfc = 0.0f, sxc = 0.0f, scrc = 0.0f;
    bool havex = false;
    int bc = 0; unsigned TBc = 0;
    for (int f = f0 + t; f < f0 + FPB; f += 256) {
        float4 v = cls4[f];
        float va[4] = {v.x, v.y, v.z, v.w};
        unsigned e0 = 4u * (unsigned)f;
        #pragma unroll
        for (int j = 0; j < 4; j++) {
            float ck = va[j];
            if (ck <= -0.001f) continue;   // cannot reach the exact gate
            unsigned e = e0 + (unsigned)j;
            unsigned p = e / NCLS;
            unsigned k = e - p * NCLS;
            if (k == 10u) continue;
            if (p != pc) {
                pc = p; cgs = ctr[p]; bc = batch[p];
                sfc = sigf(cgs); havex = false;
                TBc = sTB[bc]; scrc = sSCR[bc];
            }
            float sf = sigf(ck) * sfc;
            if (sf > scrc) {                           // rare screen pass
                if (!havex) { sxc = sigx(cgs); havex = true; }
                float s = sigx(ck) * sxc;              // exact f32 chain
                unsigned bits = __float_as_uint(s);
                if (bits >= TBc && s > 0.05f) {
                    u64 key = ((u64)bits << 32) | (u64)(0xFFFFFFFFu - e);
                    unsigned slot = atomicAdd(&lcnt[bc], 1u);
                    if (slot < LCAP) lbuf[bc][slot] = key;
                    else {                             // overflow fallback (exact)
                        unsigned pos = atomicAdd(&gcnt[bc * 16], 1u);
                        if (pos < CAP) cand[(size_t)bc * CAP + pos] = key;
                    }
                }
            }
        }
    }
    __syncthreads();
    if (t < NIMG) {
        unsigned n = lcnt[t]; if (n > LCAP) n = LCAP;
        lcnt[t] = n;
        lbase[t] = n ? atomicAdd(&gcnt[t * 16], n) : 0u;
    }
    __syncthreads();
    for (int s = t; s < NIMG * LCAP; s += 256) {
        int im = s >> 6;                   // LCAP == 64
        int sl = s & (LCAP - 1);
        if (sl < (int)lcnt[im]) {
            unsigned pos = lbase[im] + (unsigned)sl;
            if (pos < CAP) cand[(size_t)im * CAP + pos] = lbuf[im][sl];
        }
    }
}

// ---- exact sort + f32 box build (bit-exact np f32 op order) ------------
__global__ __launch_bounds__(1024)
void k_build(const unsigned long long* __restrict__ cand, const unsigned* __restrict__ gcnt,
             const float* __restrict__ loc, const float* __restrict__ breg,
             const int* __restrict__ levels, const int* __restrict__ imsz,
             float* __restrict__ bx, float* __restrict__ sc, int* __restrict__ cl,
             unsigned* __restrict__ k0, float* __restrict__ bo, float* __restrict__ ar) {
    int img = blockIdx.x;
    __shared__ unsigned long long skey[SORTN];
    __shared__ float red[1024];
    __shared__ float smc;
    unsigned n = gcnt[img * 16]; if (n > SORTN) n = SORTN;
    for (int i = threadIdx.x; i < SORTN; i += 1024)
        skey[i] = (i < (int)n) ? cand[(size_t)img * CAP + i] : 0ull;
    __syncthreads();
    for (unsigned kk = 2; kk <= SORTN; kk <<= 1) {
        for (unsigned j = kk >> 1; j > 0; j >>= 1) {
            for (unsigned i = threadIdx.x; i < SORTN; i += 1024) {
                unsigned ixj = i ^ j;
                if (ixj > i) {
                    unsigned long long a = skey[i], b = skey[ixj];
                    bool up = ((i & kk) == 0);
                    bool sw = up ? (a < b) : (a > b);   // descending (keys unique)
                    if (sw) { skey[i] = b; skey[ixj] = a; }
                }
            }
            __syncthreads();
        }
    }
    float wmax = (float)imsz[img * 2 + 1] - 1.0f;   // hw = [h, w] -> w-1
    float hmax = (float)imsz[img * 2 + 0] - 1.0f;
    float lmax = 0.0f;
    for (int r = threadIdx.x; r < TOPN; r += 1024) {
        unsigned long long kv = skey[r];
        unsigned bits = (unsigned)(kv >> 32);
        unsigned idx = 0xFFFFFFFFu - (unsigned)(kv & 0xFFFFFFFFull);
        float v = __uint_as_float(bits);
        bool v0 = (kv != 0ull) && (v > 0.0f);
        if (!v0) idx = 0;
        unsigned pt = idx / NCLS;
        int c = (int)(idx - pt * NCLS);
        float lx = loc[(size_t)pt * 2 + 0], ly = loc[(size_t)pt * 2 + 1];
        float st = (float)(8 << levels[pt]);        // 8..128, pow2 -> exact scaling
        float r0 = breg[(size_t)pt * 4 + 0] * st;
        float r1 = breg[(size_t)pt * 4 + 1] * st;
        float r2 = breg[(size_t)pt * 4 + 2] * st;
        float r3 = breg[(size_t)pt * 4 + 3] * st;
        float x1 = lx - r0, y1 = ly - r1, x2 = lx + r2, y2 = ly + r3;
        x1 = fminf(fmaxf(x1, 0.0f), wmax);
        y1 = fminf(fmaxf(y1, 0.0f), hmax);
        x2 = fminf(fmaxf(x2, 0.0f), wmax);
        y2 = fminf(fmaxf(y2, 0.0f), hmax);
        float wss = (x2 - x1) + 1.0f, hss = (y2 - y1) + 1.0f;
        bool keep = v0 && (wss >= 0.0f) && (hss >= 0.0f);
        size_t ob = (size_t)img * TOPN + r;
        bx[ob * 4 + 0] = x1; bx[ob * 4 + 1] = y1;
        bx[ob * 4 + 2] = x2; bx[ob * 4 + 3] = y2;
        sc[ob] = v0 ? sqrtf(v) : 0.0f;
        cl[ob] = c + 1;
        k0[ob] = keep ? 1u : 0u;
        if (keep) lmax = fmaxf(lmax, fmaxf(fmaxf(x1, y1), fmaxf(x2, y2)));
    }
    red[threadIdx.x] = lmax; __syncthreads();
    for (int sft = 512; sft > 0; sft >>= 1) {
        if ((int)threadIdx.x < sft) red[threadIdx.x] = fmaxf(red[threadIdx.x], red[threadIdx.x + sft]);
        __syncthreads();
    }
    if (threadIdx.x == 0) smc = red[0];
    __syncthreads();
    float off1 = smc + 1.0f;                        // max_coord + 1.0 (f32)
    for (int r = threadIdx.x; r < TOPN; r += 1024) {
        size_t ob = (size_t)img * TOPN + r;
        float o = (float)cl[ob] * off1;             // cl.astype(f32) * (mc+1)
        float x1 = bx[ob * 4 + 0] + o, y1 = bx[ob * 4 + 1] + o;
        float x2 = bx[ob * 4 + 2] + o, y2 = bx[ob * 4 + 3] + o;
        bo[ob * 4 + 0] = x1; bo[ob * 4 + 1] = y1;
        bo[ob * 4 + 2] = x2; bo[ob * 4 + 3] = y2;
        float aw = fmaxf((x2 - x1) + 1.0f, 0.0f);   // clip(x2-x1+1, 0)
        float ah = fmaxf((y2 - y1) + 1.0f, 0.0f);
        ar[ob] = aw * ah;
    }
}

// ---- IoU suppression bitmask, strictly-upper triangle ------------------
__global__ __launch_bounds__(1024)
void k_iou(const float* __restrict__ bo, const float* __restrict__ ar,
           u64* __restrict__ sup) {
    int img = blockIdx.x >> 4;
    int c   = blockIdx.x & 15;
    __shared__ float sx1[1024], sy1[1024], sx2[1024], sy2[1024], sa[1024];
    int tid = threadIdx.x;
    {
        int i = tid;
        if (i < TOPN) {
            size_t ob = (size_t)img * TOPN + i;
            sx1[i] = bo[ob * 4 + 0]; sy1[i] = bo[ob * 4 + 1];
            sx2[i] = bo[ob * 4 + 2]; sy2[i] = bo[ob * 4 + 3];
            sa[i]  = ar[ob];
        } else {
            sx1[i] = 0.0f; sy1[i] = 0.0f; sx2[i] = 0.0f; sy2[i] = 0.0f; sa[i] = 0.0f;
        }
    }
    __syncthreads();
    int width = 16 - c;
    int items = 64 * width;
    u64* supc = sup + (size_t)img * SUPW_PER_IMG + chunk_base(c);
    for (int it = tid; it < items; it += 1024) {
        int r  = it & 63;
        int wq = c + (it >> 6);
        int i  = c * 64 + r;
        if (i >= TOPN) continue;
        float x1 = sx1[i], y1 = sy1[i], x2 = sx2[i], y2 = sy2[i], a = sa[i];
        int j0 = wq * 64;
        u64 m = 0ull;
        #pragma unroll 8
        for (int jj = 0; jj < 64; jj++) {
            int j = j0 + jj;
            float xx1 = fmaxf(x1, sx1[j]);
            float yy1 = fmaxf(y1, sy1[j]);
            float xx2 = fminf(x2, sx2[j]);
            float yy2 = fminf(y2, sy2[j]);
            float iw = fmaxf((xx2 - xx1) + 1.0f, 0.0f);
            float ih = fmaxf((yy2 - yy1) + 1.0f, 0.0f);
            float inter = iw * ih;
            float den = fmaxf((a + sa[j]) - inter, 1e-9f);  // ref assoc order
            if (inter / den > 0.6f) m |= (1ull << jj);
        }
        u64 vm = ~0ull;
        if (wq == c) vm = (r >= 63) ? 0ull : (~0ull << (r + 1));   // j > i
        int rem = TOPN - j0;                                        // j < TOPN
        if (rem < 64) vm &= (rem <= 0) ? 0ull : ((1ull << rem) - 1ull);
        supc[(size_t)r * width + (wq - c)] = m & vm;
    }
}

// ---- all-register NMS scan helpers -------------------------------------
// lane L = rg*16+w holds word w of rows rg*16..rg*16+15 of the chunk.
__device__ __forceinline__ void scan_pref(const u64* __restrict__ supi, int rg, int w,
                                          int C, u64 (&V)[16]) {
    int wd = 16 - C;
    const u64* rb = supi + chunk_base(C) + (rg << 4) * wd - C + w;
    #pragma unroll
    for (int i = 0; i < 16; i++) {
        u64 x = rb[i * wd];                 // in-bounds even when w<C (masked)
        V[i] = (w >= C) ? x : 0ull;
    }
}

__device__ __forceinline__ void scan_step(int rg, int w, int C,
                                          u64 (&V)[16], u64 (&kws)[16]) {
    // m = kws[C] without dynamic register indexing
    u64 m = 0ull;
    #pragma unroll
    for (int q = 0; q < 16; q++) m |= (q == C) ? kws[q] : 0ull;
    // redistribute diagonal: lane r gets word C of row r
    u64 dmy = 0ull;
    #pragma unroll
    for (int i = 0; i < 16; i++) {
        u64 x = __shfl(V[i], (rg << 4) + C);
        if (w == i) dmy = x;
    }
    // serial 64-row scan on the diagonal only (greedy order; diag has j>i bits)
    #pragma unroll 8
    for (int r = 0; r < 64; r++) {
        u64 d  = __shfl(dmy, r);
        u64 on = (u64)0 - ((m >> r) & 1ull);
        m &= ~(d & on);
    }
    // parallel apply: kws[w'] &= ~OR_{r in m} row_r[w']
    u64 loc = 0ull;
    #pragma unroll
    for (int i = 0; i < 16; i++) {
        int row = (rg << 4) + i;
        loc |= V[i] & ((u64)0 - ((m >> row) & 1ull));
    }
    u64 t1 = loc | __shfl_xor(loc, 16);
    u64 t2 = t1 | __shfl_xor(t1, 32);
    #pragma unroll
    for (int q = 0; q < 16; q++) {
        u64 orw  = __shfl(t2, q);
        u64 base = (q == C) ? m : kws[q];
        kws[q] = base & ~orw;
    }
}

// ---- single-wave all-register bitmask scan + wave-parallel output ------
__global__ __launch_bounds__(64)
void k_scan_out(const u64* __restrict__ sup, const unsigned* __restrict__ k0,
                const float* __restrict__ bx, const float* __restrict__ sc,
                const int* __restrict__ cl, float* __restrict__ out) {
    int img = blockIdx.x;
    int t = threadIdx.x;
    int rg = t >> 4, w = t & 15;
    const u64* supi = sup + (size_t)img * SUPW_PER_IMG;

    // replicated keep words (ballot returns the same u64 to all lanes)
    u64 kws[16];
    #pragma unroll
    for (int q = 0; q < 16; q++) {
        int i = (q << 6) + t;
        unsigned vv = (i < TOPN) ? k0[(size_t)img * TOPN + i] : 0u;
        kws[q] = __ballot(vv != 0u);
    }

    u64 vA[16], vB[16];
    scan_pref(supi, rg, w, 0, vA);
    for (int c = 0; c < 16; c += 2) {
        scan_pref(supi, rg, w, c + 1, vB);   // loads fly under STEP(vA)
        scan_step(rg, w, c, vA, kws);
        if (c + 2 < 16) scan_pref(supi, rg, w, c + 2, vA);
        scan_step(rg, w, c + 1, vB, kws);
    }

    // wave-parallel stable fill via popcount ranks (kept first, then rest)
    __shared__ int fi[OUTN];
    int total_k = 0;
    #pragma unroll
    for (int q = 0; q < 16; q++) total_k += __popcll(kws[q]);
    int snk = total_k < OUTN ? total_k : OUTN;
    int run = 0;
    #pragma unroll
    for (int q = 0; q < 16; q++) {
        u64 word = kws[q];
        int i = (q << 6) + t;
        int kb = __popcll(word & ((1ull << t) - 1ull));
        bool kept = ((word >> t) & 1ull) != 0ull;
        int krank = run + kb;                // kept rows before i
        if (kept) {
            if (krank < OUTN) fi[krank] = i;
        } else if (i < TOPN) {
            int slot = snk + (i - krank);    // non-kept rank = i - kept_before
            if (slot < OUTN) fi[slot] = i;
        }
        run += __popcll(word);
    }
    __syncthreads();

    for (int q = t; q < OUTN; q += 64) {
        int r = fi[q];
        bool kv = q < snk;
        size_t ob = (size_t)img * TOPN + r;
        float sv = kv ? sc[ob] : 0.0f;
        int o = img * OUTN + q;
        out[o * 4 + 0] = bfr(bx[ob * 4 + 0]);
        out[o * 4 + 1] = bfr(bx[ob * 4 + 1]);
        out[o * 4 + 2] = bfr(bx[ob * 4 + 2]);
        out[o * 4 + 3] = bfr(bx[ob * 4 + 3]);
        out[6400 + o] = bfr(sv);
        out[8000 + o] = (float)cl[ob];
        out[9600 + o] = (sv > 0.0f) ? 1.0f : 0.0f;
    }
}

extern "C" void kernel_launch(void* const* d_in, const int* in_sizes, int n_in,
                              void* d_out, int out_size, void* d_ws, size_t ws_size,
                              hipStream_t stream) {
    const float* loc    = (const float*)d_in[0];
    const int*   levels = (const int*)d_in[1];
    const int*   batch  = (const int*)d_in[2];
    const float* cls    = (const float*)d_in[3];
    const float* breg   = (const float*)d_in[4];
    const float* ctr    = (const float*)d_in[5];
    const int*   imsz   = (const int*)d_in[6];

    char* ws = (char*)d_ws;
    unsigned long long* cand   = (unsigned long long*)(ws + 0);        // 524288
    unsigned*           ghist  = (unsigned*)(ws + 524288);             // 16*1040*4 = 66560 (region reserved 327680)
    float*              bx     = (float*)(ws + 852096);                // 256000
    float*              bo     = (float*)(ws + 1108096);               // 256000
    float*              ar     = (float*)(ws + 1364096);               // 64000
    float*              sc     = (float*)(ws + 1428096);               // 64000
    int*                cl     = (int*)(ws + 1492096);                 // 64000
    unsigned*           k0     = (unsigned*)(ws + 1556096);            // 64000
    unsigned*           gcnt   = (unsigned*)(ws + 1620096);            // 1024 (16 imgs x 64B line)
    unsigned*           thrbuf = (unsigned*)(ws + 1621120);            // 128
    u64*                sup    = (u64*)(ws + 1703936);                 // 1114112 (end 2818048 = proven envelope)
    float* out = (float*)d_out;

    hipMemsetAsync(ghist, 0, 16 * NB2P * 4, stream);
    hipMemsetAsync(gcnt, 0, 1024, stream);
    k_hist    <<<512,  1024, 0, stream>>>((const float4*)cls, ctr, batch, ghist);
    k_thresh  <<<16,   256,  0, stream>>>(ghist, thrbuf);
    k_collect <<<2048, 256,  0, stream>>>((const float4*)cls, ctr, batch, thrbuf, gcnt, cand);
    k_build   <<<16,   1024, 0, stream>>>(cand, gcnt, loc, breg, levels, imsz,
                                          bx, sc, cl, k0, bo, ar);
    k_iou     <<<256,  1024, 0, stream>>>(bo, ar, sup);
    k_scan_out<<<16,   64,   0, stream>>>(sup, k0, bx, sc, cl, out);
}

// Round 8
// 336.465 us; speedup vs baseline: 1.1477x; 1.1477x over previous
//
#include <hip/hip_runtime.h>
#include <math.h>

#pragma clang fp contract(off)

#define MPTS   2097152
#define NIMG   16
#define NCLS   11
#define CUTB   0x3F000000u   /* __float_as_uint(0.5f) — histogram floor */
#define NB2    1026          /* bins covering s in [0.5, 1.0] (+guard) */
#define NB2P   1040          /* padded per-image stride */
#define MARG   96u
#define CAP    4096
#define SORTN  4096
#define TOPN   1000
#define OUTN   100
#define LCAP   64            /* per-block per-image LDS candidate slots */

typedef unsigned long long u64;

// triangular suppression-mask storage: per image, chunks c=0..15 (rows 64c..64c+63),
// each row stores words w=c..15 (j-words); chunk base in u64 words:
#define SUPW_PER_IMG 8704
__device__ __forceinline__ int chunk_base(int c) {
    return 64 * (16 * c - (c * (c - 1)) / 2);
}

// exact f32 sigmoid mirroring numpy: e = f32(exp64(-x)); 1/(1+e) in f32
__device__ inline float sigx(float x) {
    float e = (float)exp(-(double)x);
    return 1.0f / (1.0f + e);
}
// fast screen-only sigmoid (v_exp + v_rcp, ~2-3 ulp; margins are >=96 codes)
__device__ inline float sigf(float x) {
    float e = __expf(-x);
    return __builtin_amdgcn_rcpf(1.0f + e);
}
// round f32 -> bf16 (RNE) -> f32, to match the bf16-quantized reference
__device__ inline float bfr(float x) {
    unsigned u = __float_as_uint(x);
    unsigned r = (u + 0x7FFFu + ((u >> 16) & 1u)) & 0xFFFF0000u;
    return __uint_as_float(r);
}
// uniform-lane u64 broadcast via v_readlane (no LDS round trip)
__device__ __forceinline__ u64 rdlane64(u64 v, int l) {
    unsigned lo = (unsigned)__builtin_amdgcn_readlane((int)(unsigned)(v & 0xFFFFFFFFull), l);
    unsigned hi = (unsigned)__builtin_amdgcn_readlane((int)(unsigned)(v >> 32), l);
    return ((u64)hi << 32) | (u64)lo;
}

// ---- pass A: per-image FAST histogram of score bits, range [0.5, 1.0] ---
__global__ __launch_bounds__(1024)
void k_hist(const float4* __restrict__ cls4, const float* __restrict__ ctr,
            const int* __restrict__ batch, unsigned* __restrict__ ghist) {
    __shared__ unsigned hist[NB2];
    __shared__ int simg;
    const int F4  = MPTS * NCLS / 4;       // 5767168 float4s
    const int FPB = F4 / 512;              // 11264 per block
    int f0 = blockIdx.x * FPB;
    int t = threadIdx.x;
    for (int i = t; i < NB2; i += 1024) hist[i] = 0;
    if (t == 0) simg = batch[(unsigned)(4u * (unsigned)f0) / NCLS];
    __syncthreads();
    int bi = simg;
    unsigned pc = 0xFFFFFFFFu;             // cached point
    float sfc = 0.0f;
    int bc = 0;
    for (int f = f0 + t; f < f0 + FPB; f += 1024) {
        float4 v = cls4[f];
        float va[4] = {v.x, v.y, v.z, v.w};
        unsigned e0 = 4u * (unsigned)f;
        #pragma unroll
        for (int j = 0; j < 4; j++) {
            float ck = va[j];
            if (ck <= 0.0f) continue;      // s <= 0.5: below histogram range
            unsigned e = e0 + (unsigned)j;
            unsigned p = e / NCLS;
            unsigned k = e - p * NCLS;
            if (k == 10u) continue;        // class 10 zeroed by ref
            if (p != pc) {
                pc = p; sfc = sigf(ctr[p]); bc = batch[p];
            }
            unsigned fb = __float_as_uint(sigf(ck) * sfc);
            if (fb < CUTB) continue;
            unsigned bin = (fb - CUTB) >> 13;
            if (bin >= NB2) bin = NB2 - 1;             // s==1.0 guard
            if (bc == bi) atomicAdd(&hist[bin], 1u);
            else          atomicAdd(&ghist[(size_t)bc * NB2P + bin], 1u);
        }
    }
    __syncthreads();
    unsigned* gh = ghist + (size_t)bi * NB2P;
    for (int i = t; i < NB2; i += 1024) {
        unsigned v2 = hist[i];
        if (v2) atomicAdd(&gh[i], v2);
    }
}

// ---- threshold: largest bin B with fast-suffix-count >= TOPN -----------
__global__ void k_thresh(const unsigned* __restrict__ ghist, unsigned* __restrict__ thrbuf) {
    int img = blockIdx.x;
    const unsigned* h = ghist + (size_t)img * NB2P;
    __shared__ unsigned psum[256];
    int t = threadIdx.x;
    unsigned s = 0;
    int base = t * 5;                      // 5 bins/thread, threads 0..205 cover 1026
    for (int i = 0; i < 5; i++) { int b = base + i; if (b < NB2) s += h[b]; }
    psum[t] = s;
    __syncthreads();
    if (t == 0) {
        unsigned run = 0; int B = 0;
        for (int u = 205; u >= 0; u--) {
            if (run + psum[u] >= (unsigned)TOPN) {
                int btop = u * 5 + 4; if (btop > NB2 - 1) btop = NB2 - 1;
                for (int b = btop; b >= u * 5; b--) {
                    run += h[b];
                    if (run >= (unsigned)TOPN) { B = b; break; }
                }
                break;
            }
            run += psum[u];
        }
        unsigned TB = CUTB + ((unsigned)B << 13) - MARG;   // fast->exact slack
        thrbuf[2 * img] = TB;
        thrbuf[2 * img + 1] = __float_as_uint(__uint_as_float(TB) * 0.998f); // screen
    }
}

// ---- pass B: collect u64 keys, LDS-staged (privatized counters) --------
__global__ __launch_bounds__(256)
void k_collect(const float4* __restrict__ cls4, const float* __restrict__ ctr,
               const int* __restrict__ batch, const unsigned* __restrict__ thrbuf,
               unsigned* __restrict__ gcnt, unsigned long long* __restrict__ cand) {
    __shared__ unsigned sTB[NIMG];
    __shared__ float sSCR[NIMG];
    __shared__ u64 lbuf[NIMG][LCAP];
    __shared__ unsigned lcnt[NIMG];
    __shared__ unsigned lbase[NIMG];
    int t = threadIdx.x;
    if (t < NIMG) {
        sTB[t]  = thrbuf[2 * t];
        sSCR[t] = __uint_as_float(thrbuf[2 * t + 1]);
        lcnt[t] = 0;
    }
    __syncthreads();
    const int F4  = MPTS * NCLS / 4;       // 5767168
    const int FPB = F4 / 2048;             // 2816 per block
    int f0 = blockIdx.x * FPB;
    unsigned pc = 0xFFFFFFFFu;
    float cgs = 0.0f, sfc = 0.0f, sxc = 0.0f, scrc = 0.0f;
    bool havex = false;
    int bc = 0; unsigned TBc = 0;
    for (int f = f0 + t; f < f0 + FPB; f += 256) {
        float4 v = cls4[f];
        float va[4] = {v.x, v.y, v.z, v.w};
        unsigned e0 = 4u * (unsigned)f;
        #pragma unroll
        for (int j = 0; j < 4; j++) {
            float ck = va[j];
            if (ck <= -0.001f) continue;   // cannot reach the exact gate
            unsigned e = e0 + (unsigned)j;
            unsigned p = e / NCLS;
            unsigned k = e - p * NCLS;
            if (k == 10u) continue;
            if (p != pc) {
                pc = p; cgs = ctr[p]; bc = batch[p];
                sfc = sigf(cgs); havex = false;
                TBc = sTB[bc]; scrc = sSCR[bc];
            }
            float sf = sigf(ck) * sfc;
            if (sf > scrc) {                           // rare screen pass
                if (!havex) { sxc = sigx(cgs); havex = true; }
                float s = sigx(ck) * sxc;              // exact f32 chain
                unsigned bits = __float_as_uint(s);
                if (bits >= TBc && s > 0.05f) {
                    u64 key = ((u64)bits << 32) | (u64)(0xFFFFFFFFu - e);
                    unsigned slot = atomicAdd(&lcnt[bc], 1u);
                    if (slot < LCAP) lbuf[bc][slot] = key;
                    else {                             // overflow fallback (exact)
                        unsigned pos = atomicAdd(&gcnt[bc * 16], 1u);
                        if (pos < CAP) cand[(size_t)bc * CAP + pos] = key;
                    }
                }
            }
        }
    }
    __syncthreads();
    if (t < NIMG) {
        unsigned n = lcnt[t]; if (n > LCAP) n = LCAP;
        lcnt[t] = n;
        lbase[t] = n ? atomicAdd(&gcnt[t * 16], n) : 0u;
    }
    __syncthreads();
    for (int s = t; s < NIMG * LCAP; s += 256) {
        int im = s >> 6;                   // LCAP == 64
        int sl = s & (LCAP - 1);
        if (sl < (int)lcnt[im]) {
            unsigned pos = lbase[im] + (unsigned)sl;
            if (pos < CAP) cand[(size_t)im * CAP + pos] = lbuf[im][sl];
        }
    }
}

// ---- exact sort + f32 box build (bit-exact np f32 op order) ------------
__global__ __launch_bounds__(1024)
void k_build(const unsigned long long* __restrict__ cand, const unsigned* __restrict__ gcnt,
             const float* __restrict__ loc, const float* __restrict__ breg,
             const int* __restrict__ levels, const int* __restrict__ imsz,
             float* __restrict__ bx, float* __restrict__ sc, int* __restrict__ cl,
             unsigned* __restrict__ k0, float* __restrict__ bo, float* __restrict__ ar) {
    int img = blockIdx.x;
    __shared__ unsigned long long skey[SORTN];
    __shared__ float red[1024];
    __shared__ float smc;
    unsigned n = gcnt[img * 16]; if (n > SORTN) n = SORTN;
    for (int i = threadIdx.x; i < SORTN; i += 1024)
        skey[i] = (i < (int)n) ? cand[(size_t)img * CAP + i] : 0ull;
    __syncthreads();
    for (unsigned kk = 2; kk <= SORTN; kk <<= 1) {
        for (unsigned j = kk >> 1; j > 0; j >>= 1) {
            for (unsigned i = threadIdx.x; i < SORTN; i += 1024) {
                unsigned ixj = i ^ j;
                if (ixj > i) {
                    unsigned long long a = skey[i], b = skey[ixj];
                    bool up = ((i & kk) == 0);
                    bool sw = up ? (a < b) : (a > b);   // descending (keys unique)
                    if (sw) { skey[i] = b; skey[ixj] = a; }
                }
            }
            __syncthreads();
        }
    }
    float wmax = (float)imsz[img * 2 + 1] - 1.0f;   // hw = [h, w] -> w-1
    float hmax = (float)imsz[img * 2 + 0] - 1.0f;
    float lmax = 0.0f;
    for (int r = threadIdx.x; r < TOPN; r += 1024) {
        unsigned long long kv = skey[r];
        unsigned bits = (unsigned)(kv >> 32);
        unsigned idx = 0xFFFFFFFFu - (unsigned)(kv & 0xFFFFFFFFull);
        float v = __uint_as_float(bits);
        bool v0 = (kv != 0ull) && (v > 0.0f);
        if (!v0) idx = 0;
        unsigned pt = idx / NCLS;
        int c = (int)(idx - pt * NCLS);
        float lx = loc[(size_t)pt * 2 + 0], ly = loc[(size_t)pt * 2 + 1];
        float st = (float)(8 << levels[pt]);        // 8..128, pow2 -> exact scaling
        float r0 = breg[(size_t)pt * 4 + 0] * st;
        float r1 = breg[(size_t)pt * 4 + 1] * st;
        float r2 = breg[(size_t)pt * 4 + 2] * st;
        float r3 = breg[(size_t)pt * 4 + 3] * st;
        float x1 = lx - r0, y1 = ly - r1, x2 = lx + r2, y2 = ly + r3;
        x1 = fminf(fmaxf(x1, 0.0f), wmax);
        y1 = fminf(fmaxf(y1, 0.0f), hmax);
        x2 = fminf(fmaxf(x2, 0.0f), wmax);
        y2 = fminf(fmaxf(y2, 0.0f), hmax);
        float wss = (x2 - x1) + 1.0f, hss = (y2 - y1) + 1.0f;
        bool keep = v0 && (wss >= 0.0f) && (hss >= 0.0f);
        size_t ob = (size_t)img * TOPN + r;
        bx[ob * 4 + 0] = x1; bx[ob * 4 + 1] = y1;
        bx[ob * 4 + 2] = x2; bx[ob * 4 + 3] = y2;
        sc[ob] = v0 ? sqrtf(v) : 0.0f;
        cl[ob] = c + 1;
        k0[ob] = keep ? 1u : 0u;
        if (keep) lmax = fmaxf(lmax, fmaxf(fmaxf(x1, y1), fmaxf(x2, y2)));
    }
    red[threadIdx.x] = lmax; __syncthreads();
    for (int sft = 512; sft > 0; sft >>= 1) {
        if ((int)threadIdx.x < sft) red[threadIdx.x] = fmaxf(red[threadIdx.x], red[threadIdx.x + sft]);
        __syncthreads();
    }
    if (threadIdx.x == 0) smc = red[0];
    __syncthreads();
    float off1 = smc + 1.0f;                        // max_coord + 1.0 (f32)
    for (int r = threadIdx.x; r < TOPN; r += 1024) {
        size_t ob = (size_t)img * TOPN + r;
        float o = (float)cl[ob] * off1;             // cl.astype(f32) * (mc+1)
        float x1 = bx[ob * 4 + 0] + o, y1 = bx[ob * 4 + 1] + o;
        float x2 = bx[ob * 4 + 2] + o, y2 = bx[ob * 4 + 3] + o;
        bo[ob * 4 + 0] = x1; bo[ob * 4 + 1] = y1;
        bo[ob * 4 + 2] = x2; bo[ob * 4 + 3] = y2;
        float aw = fmaxf((x2 - x1) + 1.0f, 0.0f);   // clip(x2-x1+1, 0)
        float ah = fmaxf((y2 - y1) + 1.0f, 0.0f);
        ar[ob] = aw * ah;
    }
}

// ---- IoU suppression bitmask, strictly-upper triangle ------------------
__global__ __launch_bounds__(1024)
void k_iou(const float* __restrict__ bo, const float* __restrict__ ar,
           u64* __restrict__ sup) {
    int img = blockIdx.x >> 4;
    int c   = blockIdx.x & 15;
    __shared__ float sx1[1024], sy1[1024], sx2[1024], sy2[1024], sa[1024];
    int tid = threadIdx.x;
    {
        int i = tid;
        if (i < TOPN) {
            size_t ob = (size_t)img * TOPN + i;
            sx1[i] = bo[ob * 4 + 0]; sy1[i] = bo[ob * 4 + 1];
            sx2[i] = bo[ob * 4 + 2]; sy2[i] = bo[ob * 4 + 3];
            sa[i]  = ar[ob];
        } else {
            sx1[i] = 0.0f; sy1[i] = 0.0f; sx2[i] = 0.0f; sy2[i] = 0.0f; sa[i] = 0.0f;
        }
    }
    __syncthreads();
    int width = 16 - c;
    int items = 64 * width;
    u64* supc = sup + (size_t)img * SUPW_PER_IMG + chunk_base(c);
    for (int it = tid; it < items; it += 1024) {
        int r  = it & 63;
        int wq = c + (it >> 6);
        int i  = c * 64 + r;
        if (i >= TOPN) continue;
        float x1 = sx1[i], y1 = sy1[i], x2 = sx2[i], y2 = sy2[i], a = sa[i];
        int j0 = wq * 64;
        u64 m = 0ull;
        #pragma unroll 8
        for (int jj = 0; jj < 64; jj++) {
            int j = j0 + jj;
            float xx1 = fmaxf(x1, sx1[j]);
            float yy1 = fmaxf(y1, sy1[j]);
            float xx2 = fminf(x2, sx2[j]);
            float yy2 = fminf(y2, sy2[j]);
            float iw = fmaxf((xx2 - xx1) + 1.0f, 0.0f);
            float ih = fmaxf((yy2 - yy1) + 1.0f, 0.0f);
            float inter = iw * ih;
            float den = fmaxf((a + sa[j]) - inter, 1e-9f);  // ref assoc order
            if (inter / den > 0.6f) m |= (1ull << jj);
        }
        u64 vm = ~0ull;
        if (wq == c) vm = (r >= 63) ? 0ull : (~0ull << (r + 1));   // j > i
        int rem = TOPN - j0;                                        // j < TOPN
        if (rem < 64) vm &= (rem <= 0) ? 0ull : ((1ull << rem) - 1ull);
        supc[(size_t)r * width + (wq - c)] = m & vm;
    }
}

// ---- NMS scan helpers (sparse diagonal + distributed keep-vector) ------
// lane L = rg*16+w holds word w of rows rg*16..rg*16+15 of the chunk;
// lane r additionally prefetches the diagonal word of row r directly.
__device__ __forceinline__ void scan_pref(const u64* __restrict__ supi, int rg, int w, int t,
                                          int C, u64 (&V)[16], u64 &anyV, u64 &dmy) {
    int wd = 16 - C;
    const u64* rb = supi + chunk_base(C) + (rg << 4) * wd - C + w;
    u64 a = 0ull;
    #pragma unroll
    for (int i = 0; i < 16; i++) {
        u64 x = rb[i * wd];                 // in-bounds even when w<C (masked)
        V[i] = (w >= C) ? x : 0ull;
        a |= V[i];
    }
    anyV = a;
    dmy = supi[chunk_base(C) + (size_t)t * wd];   // word C of row t (diagonal)
}

// Greedy-exact chunk step. Serial part visits ONLY rows with a nonzero
// diagonal word that are still kept (act ⊆ m maintained); same order, same
// result as the dense scan. kw_local is the keep word (t&15), replicated
// across the 4 row-groups; apply is lane-local (no broadcast shfls).
__device__ __forceinline__ void scan_step(int rg, int w, int C,
                                          u64 (&V)[16], u64 anyV, u64 dmy,
                                          u64 &kw_local) {
    u64 m = rdlane64(kw_local, C);            // word C (lane C: rg=0,w=C)
    u64 act = __ballot(dmy != 0ull) & m;
    while (act) {
        int r = __builtin_ctzll(act);
        u64 d = rdlane64(dmy, r);
        m &= ~d;                              // diag has only j>r bits
        act &= act - 1ull;
        act &= m;                             // drop rows suppressed by r
    }
    if (__ballot(anyV != 0ull)) {
        u64 loc = 0ull;
        #pragma unroll
        for (int i = 0; i < 16; i++) {
            int row = (rg << 4) + i;
            loc |= V[i] & ((u64)0 - ((m >> row) & 1ull));
        }
        u64 t1 = loc | __shfl_xor(loc, 16);
        u64 t2 = t1 | __shfl_xor(t1, 32);     // word-w OR over all 64 rows
        kw_local = ((w == C) ? m : kw_local) & ~t2;  // t2==0 for w<C
    } else if (w == C) {
        kw_local = m;
    }
}

// ---- single-wave sparse bitmask scan + wave-parallel output ------------
__global__ __launch_bounds__(64)
void k_scan_out(const u64* __restrict__ sup, const unsigned* __restrict__ k0,
                const float* __restrict__ bx, const float* __restrict__ sc,
                const int* __restrict__ cl, float* __restrict__ out) {
    int img = blockIdx.x;
    int t = threadIdx.x;
    int rg = t >> 4, w = t & 15;
    const u64* supi = sup + (size_t)img * SUPW_PER_IMG;

    // distributed keep words: lane L holds word L&15 (replicated across rg)
    u64 kw_local = 0ull;
    #pragma unroll
    for (int q = 0; q < 16; q++) {
        int i = (q << 6) + t;
        unsigned vv = (i < TOPN) ? k0[(size_t)img * TOPN + i] : 0u;
        u64 bal = __ballot(vv != 0u);
        if (w == q) kw_local = bal;
    }

    u64 vA[16], vB[16], anyA, anyB, dA, dB;
    scan_pref(supi, rg, w, t, 0, vA, anyA, dA);
    for (int c = 0; c < 16; c += 2) {
        scan_pref(supi, rg, w, t, c + 1, vB, anyB, dB);  // flies under STEP(A)
        scan_step(rg, w, c, vA, anyA, dA, kw_local);
        if (c + 2 < 16) scan_pref(supi, rg, w, t, c + 2, vA, anyA, dA);
        scan_step(rg, w, c + 1, vB, anyB, dB, kw_local);
    }

    // replicated copy for the fill (literal-lane readlanes)
    u64 kws[16];
    #pragma unroll
    for (int q = 0; q < 16; q++) kws[q] = rdlane64(kw_local, q);

    // wave-parallel stable fill via popcount ranks (kept first, then rest)
    __shared__ int fi[OUTN];
    int total_k = 0;
    #pragma unroll
    for (int q = 0; q < 16; q++) total_k += __popcll(kws[q]);
    int snk = total_k < OUTN ? total_k : OUTN;
    int run = 0;
    #pragma unroll
    for (int q = 0; q < 16; q++) {
        u64 word = kws[q];
        int i = (q << 6) + t;
        int kb = __popcll(word & ((1ull << t) - 1ull));
        bool kept = ((word >> t) & 1ull) != 0ull;
        int krank = run + kb;                // kept rows before i
        if (kept) {
            if (krank < OUTN) fi[krank] = i;
        } else if (i < TOPN) {
            int slot = snk + (i - krank);    // non-kept rank = i - kept_before
            if (slot < OUTN) fi[slot] = i;
        }
        run += __popcll(word);
    }
    __syncthreads();

    for (int q = t; q < OUTN; q += 64) {
        int r = fi[q];
        bool kv = q < snk;
        size_t ob = (size_t)img * TOPN + r;
        float sv = kv ? sc[ob] : 0.0f;
        int o = img * OUTN + q;
        out[o * 4 + 0] = bfr(bx[ob * 4 + 0]);
        out[o * 4 + 1] = bfr(bx[ob * 4 + 1]);
        out[o * 4 + 2] = bfr(bx[ob * 4 + 2]);
        out[o * 4 + 3] = bfr(bx[ob * 4 + 3]);
        out[6400 + o] = bfr(sv);
        out[8000 + o] = (float)cl[ob];
        out[9600 + o] = (sv > 0.0f) ? 1.0f : 0.0f;
    }
}

extern "C" void kernel_launch(void* const* d_in, const int* in_sizes, int n_in,
                              void* d_out, int out_size, void* d_ws, size_t ws_size,
                              hipStream_t stream) {
    const float* loc    = (const float*)d_in[0];
    const int*   levels = (const int*)d_in[1];
    const int*   batch  = (const int*)d_in[2];
    const float* cls    = (const float*)d_in[3];
    const float* breg   = (const float*)d_in[4];
    const float* ctr    = (const float*)d_in[5];
    const int*   imsz   = (const int*)d_in[6];

    char* ws = (char*)d_ws;
    unsigned long long* cand   = (unsigned long long*)(ws + 0);        // 524288
    unsigned*           ghist  = (unsigned*)(ws + 524288);             // 16*1040*4 = 66560 (region reserved 327680)
    float*              bx     = (float*)(ws + 852096);                // 256000
    float*              bo     = (float*)(ws + 1108096);               // 256000
    float*              ar     = (float*)(ws + 1364096);               // 64000
    float*              sc     = (float*)(ws + 1428096);               // 64000
    int*                cl     = (int*)(ws + 1492096);                 // 64000
    unsigned*           k0     = (unsigned*)(ws + 1556096);            // 64000
    unsigned*           gcnt   = (unsigned*)(ws + 1620096);            // 1024 (16 imgs x 64B line)
    unsigned*           thrbuf = (unsigned*)(ws + 1621120);            // 128
    u64*                sup    = (u64*)(ws + 1703936);                 // 1114112 (end 2818048 = proven envelope)
    float* out = (float*)d_out;

    hipMemsetAsync(ghist, 0, 16 * NB2P * 4, stream);
    hipMemsetAsync(gcnt, 0, 1024, stream);
    k_hist    <<<512,  1024, 0, stream>>>((const float4*)cls, ctr, batch, ghist);
    k_thresh  <<<16,   256,  0, stream>>>(ghist, thrbuf);
    k_collect <<<2048, 256,  0, stream>>>((const float4*)cls, ctr, batch, thrbuf, gcnt, cand);
    k_build   <<<16,   1024, 0, stream>>>(cand, gcnt, loc, breg, levels, imsz,
                                          bx, sc, cl, k0, bo, ar);
    k_iou     <<<256,  1024, 0, stream>>>(bo, ar, sup);
    k_scan_out<<<16,   64,   0, stream>>>(sup, k0, bx, sc, cl, out);
}

// Round 9
// 320.273 us; speedup vs baseline: 1.2057x; 1.0506x over previous
//
#include <hip/hip_runtime.h>
#include <math.h>

#pragma clang fp contract(off)

#define MPTS   2097152
#define NIMG   16
#define NCLS   11
#define CUTB   0x3F000000u   /* __float_as_uint(0.5f) — histogram floor */
#define NB2    1026          /* bins covering s in [0.5, 1.0] (+guard) */
#define NB2P   1040          /* padded per-image stride */
#define MARG   96u
#define CAP    4096
#define TOPN   1000
#define OUTN   100
#define LCAP   64            /* per-block per-image LDS candidate slots */

typedef unsigned long long u64;

// triangular suppression-mask storage: per image, chunks c=0..15 (rows 64c..64c+63),
// each row stores words w=c..15 (j-words); chunk base in u64 words:
#define SUPW_PER_IMG 8704
__device__ __forceinline__ int chunk_base(int c) {
    return 64 * (16 * c - (c * (c - 1)) / 2);
}

// exact f32 sigmoid mirroring numpy: e = f32(exp64(-x)); 1/(1+e) in f32
__device__ inline float sigx(float x) {
    float e = (float)exp(-(double)x);
    return 1.0f / (1.0f + e);
}
// fast screen-only sigmoid (v_exp + v_rcp, ~2-3 ulp; margins are >=96 codes)
__device__ inline float sigf(float x) {
    float e = __expf(-x);
    return __builtin_amdgcn_rcpf(1.0f + e);
}
// round f32 -> bf16 (RNE) -> f32, to match the bf16-quantized reference
__device__ inline float bfr(float x) {
    unsigned u = __float_as_uint(x);
    unsigned r = (u + 0x7FFFu + ((u >> 16) & 1u)) & 0xFFFF0000u;
    return __uint_as_float(r);
}
// uniform-lane u64 broadcast via v_readlane (no LDS round trip)
__device__ __forceinline__ u64 rdlane64(u64 v, int l) {
    unsigned lo = (unsigned)__builtin_amdgcn_readlane((int)(unsigned)(v & 0xFFFFFFFFull), l);
    unsigned hi = (unsigned)__builtin_amdgcn_readlane((int)(unsigned)(v >> 32), l);
    return ((u64)hi << 32) | (u64)lo;
}

// ---- pass A: per-image FAST histogram of score bits, range [0.5, 1.0] ---
__global__ __launch_bounds__(1024)
void k_hist(const float4* __restrict__ cls4, const float* __restrict__ ctr,
            const int* __restrict__ batch, unsigned* __restrict__ ghist) {
    __shared__ unsigned hist[NB2];
    __shared__ int simg;
    const int F4  = MPTS * NCLS / 4;       // 5767168 float4s
    const int FPB = F4 / 512;              // 11264 per block
    int f0 = blockIdx.x * FPB;
    int t = threadIdx.x;
    for (int i = t; i < NB2; i += 1024) hist[i] = 0;
    if (t == 0) simg = batch[(unsigned)(4u * (unsigned)f0) / NCLS];
    __syncthreads();
    int bi = simg;
    unsigned pc = 0xFFFFFFFFu;             // cached point
    float sfc = 0.0f;
    int bc = 0;
    for (int f = f0 + t; f < f0 + FPB; f += 1024) {
        float4 v = cls4[f];
        float va[4] = {v.x, v.y, v.z, v.w};
        unsigned e0 = 4u * (unsigned)f;
        #pragma unroll
        for (int j = 0; j < 4; j++) {
            float ck = va[j];
            if (ck <= 0.0f) continue;      // s <= 0.5: below histogram range
            unsigned e = e0 + (unsigned)j;
            unsigned p = e / NCLS;
            unsigned k = e - p * NCLS;
            if (k == 10u) continue;        // class 10 zeroed by ref
            if (p != pc) {
                pc = p; sfc = sigf(ctr[p]); bc = batch[p];
            }
            unsigned fb = __float_as_uint(sigf(ck) * sfc);
            if (fb < CUTB) continue;
            unsigned bin = (fb - CUTB) >> 13;
            if (bin >= NB2) bin = NB2 - 1;             // s==1.0 guard
            if (bc == bi) atomicAdd(&hist[bin], 1u);
            else          atomicAdd(&ghist[(size_t)bc * NB2P + bin], 1u);
        }
    }
    __syncthreads();
    unsigned* gh = ghist + (size_t)bi * NB2P;
    for (int i = t; i < NB2; i += 1024) {
        unsigned v2 = hist[i];
        if (v2) atomicAdd(&gh[i], v2);
    }
}

// ---- threshold: largest bin B with fast-suffix-count >= TOPN -----------
__global__ void k_thresh(const unsigned* __restrict__ ghist, unsigned* __restrict__ thrbuf) {
    int img = blockIdx.x;
    const unsigned* h = ghist + (size_t)img * NB2P;
    __shared__ unsigned psum[256];
    int t = threadIdx.x;
    unsigned s = 0;
    int base = t * 5;                      // 5 bins/thread, threads 0..205 cover 1026
    for (int i = 0; i < 5; i++) { int b = base + i; if (b < NB2) s += h[b]; }
    psum[t] = s;
    __syncthreads();
    if (t == 0) {
        unsigned run = 0; int B = 0;
        for (int u = 205; u >= 0; u--) {
            if (run + psum[u] >= (unsigned)TOPN) {
                int btop = u * 5 + 4; if (btop > NB2 - 1) btop = NB2 - 1;
                for (int b = btop; b >= u * 5; b--) {
                    run += h[b];
                    if (run >= (unsigned)TOPN) { B = b; break; }
                }
                break;
            }
            run += psum[u];
        }
        unsigned TB = CUTB + ((unsigned)B << 13) - MARG;   // fast->exact slack
        thrbuf[2 * img] = TB;
        thrbuf[2 * img + 1] = __float_as_uint(__uint_as_float(TB) * 0.998f); // screen
    }
}

// ---- pass B: collect u64 keys, LDS-staged (privatized counters) --------
__global__ __launch_bounds__(256)
void k_collect(const float4* __restrict__ cls4, const float* __restrict__ ctr,
               const int* __restrict__ batch, const unsigned* __restrict__ thrbuf,
               unsigned* __restrict__ gcnt, unsigned long long* __restrict__ cand) {
    __shared__ unsigned sTB[NIMG];
    __shared__ float sSCR[NIMG];
    __shared__ u64 lbuf[NIMG][LCAP];
    __shared__ unsigned lcnt[NIMG];
    __shared__ unsigned lbase[NIMG];
    int t = threadIdx.x;
    if (t < NIMG) {
        sTB[t]  = thrbuf[2 * t];
        sSCR[t] = __uint_as_float(thrbuf[2 * t + 1]);
        lcnt[t] = 0;
    }
    __syncthreads();
    const int F4  = MPTS * NCLS / 4;       // 5767168
    const int FPB = F4 / 2048;             // 2816 per block
    int f0 = blockIdx.x * FPB;
    unsigned pc = 0xFFFFFFFFu;
    float cgs = 0.0f, sfc = 0.0f, sxc = 0.0f, scrc = 0.0f;
    bool havex = false;
    int bc = 0; unsigned TBc = 0;
    for (int f = f0 + t; f < f0 + FPB; f += 256) {
        float4 v = cls4[f];
        float va[4] = {v.x, v.y, v.z, v.w};
        unsigned e0 = 4u * (unsigned)f;
        #pragma unroll
        for (int j = 0; j < 4; j++) {
            float ck = va[j];
            if (ck <= -0.001f) continue;   // cannot reach the exact gate
            unsigned e = e0 + (unsigned)j;
            unsigned p = e / NCLS;
            unsigned k = e - p * NCLS;
            if (k == 10u) continue;
            if (p != pc) {
                pc = p; cgs = ctr[p]; bc = batch[p];
                sfc = sigf(cgs); havex = false;
                TBc = sTB[bc]; scrc = sSCR[bc];
            }
            float sf = sigf(ck) * sfc;
            if (sf > scrc) {                           // rare screen pass
                if (!havex) { sxc = sigx(cgs); havex = true; }
                float s = sigx(ck) * sxc;              // exact f32 chain
                unsigned bits = __float_as_uint(s);
                if (bits >= TBc && s > 0.05f) {
                    u64 key = ((u64)bits << 32) | (u64)(0xFFFFFFFFu - e);
                    unsigned slot = atomicAdd(&lcnt[bc], 1u);
                    if (slot < LCAP) lbuf[bc][slot] = key;
                    else {                             // overflow fallback (exact)
                        unsigned pos = atomicAdd(&gcnt[bc * 16], 1u);
                        if (pos < CAP) cand[(size_t)bc * CAP + pos] = key;
                    }
                }
            }
        }
    }
    __syncthreads();
    if (t < NIMG) {
        unsigned n = lcnt[t]; if (n > LCAP) n = LCAP;
        lcnt[t] = n;
        lbase[t] = n ? atomicAdd(&gcnt[t * 16], n) : 0u;
    }
    __syncthreads();
    for (int s = t; s < NIMG * LCAP; s += 256) {
        int im = s >> 6;                   // LCAP == 64
        int sl = s & (LCAP - 1);
        if (sl < (int)lcnt[im]) {
            unsigned pos = lbase[im] + (unsigned)sl;
            if (pos < CAP) cand[(size_t)im * CAP + pos] = lbuf[im][sl];
        }
    }
}

// ---- rank-select: barrier-free O(n^2) descending order ------------------
// Keys are unique u64s -> sorted position of key i is #{j: key_j > key_i}.
// srt is pre-zeroed; ranks >= TOPN are dropped; zeros beyond n match the
// old post-sort padding exactly (real keys are always > 0).
__global__ __launch_bounds__(1024)
void k_rank(const u64* __restrict__ cand, const unsigned* __restrict__ gcnt,
            u64* __restrict__ srt) {
    int img = blockIdx.x >> 2;
    int sub = blockIdx.x & 3;
    __shared__ u64 keys[CAP];
    unsigned n = gcnt[img * 16]; if (n > CAP) n = CAP;
    for (int i = threadIdx.x; i < (int)n; i += 1024)
        keys[i] = cand[(size_t)img * CAP + i];
    __syncthreads();
    int i = sub * 1024 + (int)threadIdx.x;
    if (i < (int)n) {
        u64 me = keys[i];
        int rank = 0;
        int j = 0;
        for (; j + 4 <= (int)n; j += 4) {   // wave-broadcast LDS reads
            rank += (keys[j]     > me);
            rank += (keys[j + 1] > me);
            rank += (keys[j + 2] > me);
            rank += (keys[j + 3] > me);
        }
        for (; j < (int)n; j++) rank += (keys[j] > me);
        if (rank < TOPN) srt[(size_t)img * TOPN + rank] = me;
    }
}

// ---- f32 box build from ranked keys (bit-exact np f32 op order) --------
__global__ __launch_bounds__(256)
void k_build(const u64* __restrict__ srt,
             const float* __restrict__ loc, const float* __restrict__ breg,
             const int* __restrict__ levels, const int* __restrict__ imsz,
             float* __restrict__ bx, float* __restrict__ sc, int* __restrict__ cl,
             unsigned* __restrict__ k0, float* __restrict__ bo, float* __restrict__ ar) {
    int img = blockIdx.x;
    __shared__ float red[256];
    __shared__ float smc;
    float wmax = (float)imsz[img * 2 + 1] - 1.0f;   // hw = [h, w] -> w-1
    float hmax = (float)imsz[img * 2 + 0] - 1.0f;
    float lmax = 0.0f;
    for (int r = threadIdx.x; r < TOPN; r += 256) {
        u64 kv = srt[(size_t)img * TOPN + r];
        unsigned bits = (unsigned)(kv >> 32);
        unsigned idx = 0xFFFFFFFFu - (unsigned)(kv & 0xFFFFFFFFull);
        float v = __uint_as_float(bits);
        bool v0 = (kv != 0ull) && (v > 0.0f);
        if (!v0) idx = 0;
        unsigned pt = idx / NCLS;
        int c = (int)(idx - pt * NCLS);
        float lx = loc[(size_t)pt * 2 + 0], ly = loc[(size_t)pt * 2 + 1];
        float st = (float)(8 << levels[pt]);        // 8..128, pow2 -> exact scaling
        float r0 = breg[(size_t)pt * 4 + 0] * st;
        float r1 = breg[(size_t)pt * 4 + 1] * st;
        float r2 = breg[(size_t)pt * 4 + 2] * st;
        float r3 = breg[(size_t)pt * 4 + 3] * st;
        float x1 = lx - r0, y1 = ly - r1, x2 = lx + r2, y2 = ly + r3;
        x1 = fminf(fmaxf(x1, 0.0f), wmax);
        y1 = fminf(fmaxf(y1, 0.0f), hmax);
        x2 = fminf(fmaxf(x2, 0.0f), wmax);
        y2 = fminf(fmaxf(y2, 0.0f), hmax);
        float wss = (x2 - x1) + 1.0f, hss = (y2 - y1) + 1.0f;
        bool keep = v0 && (wss >= 0.0f) && (hss >= 0.0f);
        size_t ob = (size_t)img * TOPN + r;
        bx[ob * 4 + 0] = x1; bx[ob * 4 + 1] = y1;
        bx[ob * 4 + 2] = x2; bx[ob * 4 + 3] = y2;
        sc[ob] = v0 ? sqrtf(v) : 0.0f;
        cl[ob] = c + 1;
        k0[ob] = keep ? 1u : 0u;
        if (keep) lmax = fmaxf(lmax, fmaxf(fmaxf(x1, y1), fmaxf(x2, y2)));
    }
    red[threadIdx.x] = lmax; __syncthreads();
    for (int sft = 128; sft > 0; sft >>= 1) {
        if ((int)threadIdx.x < sft) red[threadIdx.x] = fmaxf(red[threadIdx.x], red[threadIdx.x + sft]);
        __syncthreads();
    }
    if (threadIdx.x == 0) smc = red[0];
    __syncthreads();
    float off1 = smc + 1.0f;                        // max_coord + 1.0 (f32)
    for (int r = threadIdx.x; r < TOPN; r += 256) {
        size_t ob = (size_t)img * TOPN + r;
        float o = (float)cl[ob] * off1;             // cl.astype(f32) * (mc+1)
        float x1 = bx[ob * 4 + 0] + o, y1 = bx[ob * 4 + 1] + o;
        float x2 = bx[ob * 4 + 2] + o, y2 = bx[ob * 4 + 3] + o;
        bo[ob * 4 + 0] = x1; bo[ob * 4 + 1] = y1;
        bo[ob * 4 + 2] = x2; bo[ob * 4 + 3] = y2;
        float aw = fmaxf((x2 - x1) + 1.0f, 0.0f);   // clip(x2-x1+1, 0)
        float ah = fmaxf((y2 - y1) + 1.0f, 0.0f);
        ar[ob] = aw * ah;
    }
}

// ---- IoU suppression bitmask, strictly-upper triangle ------------------
__global__ __launch_bounds__(1024)
void k_iou(const float* __restrict__ bo, const float* __restrict__ ar,
           u64* __restrict__ sup) {
    int img = blockIdx.x >> 4;
    int c   = blockIdx.x & 15;
    __shared__ float sx1[1024], sy1[1024], sx2[1024], sy2[1024], sa[1024];
    int tid = threadIdx.x;
    {
        int i = tid;
        if (i < TOPN) {
            size_t ob = (size_t)img * TOPN + i;
            sx1[i] = bo[ob * 4 + 0]; sy1[i] = bo[ob * 4 + 1];
            sx2[i] = bo[ob * 4 + 2]; sy2[i] = bo[ob * 4 + 3];
            sa[i]  = ar[ob];
        } else {
            sx1[i] = 0.0f; sy1[i] = 0.0f; sx2[i] = 0.0f; sy2[i] = 0.0f; sa[i] = 0.0f;
        }
    }
    __syncthreads();
    int width = 16 - c;
    int items = 64 * width;
    u64* supc = sup + (size_t)img * SUPW_PER_IMG + chunk_base(c);
    for (int it = tid; it < items; it += 1024) {
        int r  = it & 63;
        int wq = c + (it >> 6);
        int i  = c * 64 + r;
        if (i >= TOPN) continue;
        float x1 = sx1[i], y1 = sy1[i], x2 = sx2[i], y2 = sy2[i], a = sa[i];
        int j0 = wq * 64;
        u64 m = 0ull;
        #pragma unroll 8
        for (int jj = 0; jj < 64; jj++) {
            int j = j0 + jj;
            float xx1 = fmaxf(x1, sx1[j]);
            float yy1 = fmaxf(y1, sy1[j]);
            float xx2 = fminf(x2, sx2[j]);
            float yy2 = fminf(y2, sy2[j]);
            float iw = fmaxf((xx2 - xx1) + 1.0f, 0.0f);
            float ih = fmaxf((yy2 - yy1) + 1.0f, 0.0f);
            float inter = iw * ih;
            float den = fmaxf((a + sa[j]) - inter, 1e-9f);  // ref assoc order
            if (inter / den > 0.6f) m |= (1ull << jj);
        }
        u64 vm = ~0ull;
        if (wq == c) vm = (r >= 63) ? 0ull : (~0ull << (r + 1));   // j > i
        int rem = TOPN - j0;                                        // j < TOPN
        if (rem < 64) vm &= (rem <= 0) ? 0ull : ((1ull << rem) - 1ull);
        supc[(size_t)r * width + (wq - c)] = m & vm;
    }
}

// ---- NMS scan helpers (sparse diagonal + distributed keep-vector) ------
__device__ __forceinline__ void scan_pref(const u64* __restrict__ supi, int rg, int w, int t,
                                          int C, u64 (&V)[16], u64 &anyV, u64 &dmy) {
    int wd = 16 - C;
    const u64* rb = supi + chunk_base(C) + (rg << 4) * wd - C + w;
    u64 a = 0ull;
    #pragma unroll
    for (int i = 0; i < 16; i++) {
        u64 x = rb[i * wd];                 // in-bounds even when w<C (masked)
        V[i] = (w >= C) ? x : 0ull;
        a |= V[i];
    }
    anyV = a;
    dmy = supi[chunk_base(C) + (size_t)t * wd];   // word C of row t (diagonal)
}

__device__ __forceinline__ void scan_step(int rg, int w, int C,
                                          u64 (&V)[16], u64 anyV, u64 dmy,
                                          u64 &kw_local) {
    u64 m = rdlane64(kw_local, C);            // word C (lane C: rg=0,w=C)
    u64 act = __ballot(dmy != 0ull) & m;
    while (act) {
        int r = __builtin_ctzll(act);
        u64 d = rdlane64(dmy, r);
        m &= ~d;                              // diag has only j>r bits
        act &= act - 1ull;
        act &= m;                             // drop rows suppressed by r
    }
    if (__ballot(anyV != 0ull)) {
        u64 loc = 0ull;
        #pragma unroll
        for (int i = 0; i < 16; i++) {
            int row = (rg << 4) + i;
            loc |= V[i] & ((u64)0 - ((m >> row) & 1ull));
        }
        u64 t1 = loc | __shfl_xor(loc, 16);
        u64 t2 = t1 | __shfl_xor(t1, 32);     // word-w OR over all 64 rows
        kw_local = ((w == C) ? m : kw_local) & ~t2;  // t2==0 for w<C
    } else if (w == C) {
        kw_local = m;
    }
}

// ---- single-wave sparse bitmask scan + wave-parallel output ------------
__global__ __launch_bounds__(64)
void k_scan_out(const u64* __restrict__ sup, const unsigned* __restrict__ k0,
                const float* __restrict__ bx, const float* __restrict__ sc,
                const int* __restrict__ cl, float* __restrict__ out) {
    int img = blockIdx.x;
    int t = threadIdx.x;
    int rg = t >> 4, w = t & 15;
    const u64* supi = sup + (size_t)img * SUPW_PER_IMG;

    // distributed keep words: lane L holds word L&15 (replicated across rg)
    u64 kw_local = 0ull;
    #pragma unroll
    for (int q = 0; q < 16; q++) {
        int i = (q << 6) + t;
        unsigned vv = (i < TOPN) ? k0[(size_t)img * TOPN + i] : 0u;
        u64 bal = __ballot(vv != 0u);
        if (w == q) kw_local = bal;
    }

    u64 vA[16], vB[16], anyA, anyB, dA, dB;
    scan_pref(supi, rg, w, t, 0, vA, anyA, dA);
    for (int c = 0; c < 16; c += 2) {
        scan_pref(supi, rg, w, t, c + 1, vB, anyB, dB);  // flies under STEP(A)
        scan_step(rg, w, c, vA, anyA, dA, kw_local);
        if (c + 2 < 16) scan_pref(supi, rg, w, t, c + 2, vA, anyA, dA);
        scan_step(rg, w, c + 1, vB, anyB, dB, kw_local);
    }

    // replicated copy for the fill (literal-lane readlanes)
    u64 kws[16];
    #pragma unroll
    for (int q = 0; q < 16; q++) kws[q] = rdlane64(kw_local, q);

    // wave-parallel stable fill via popcount ranks (kept first, then rest)
    __shared__ int fi[OUTN];
    int total_k = 0;
    #pragma unroll
    for (int q = 0; q < 16; q++) total_k += __popcll(kws[q]);
    int snk = total_k < OUTN ? total_k : OUTN;
    int run = 0;
    #pragma unroll
    for (int q = 0; q < 16; q++) {
        u64 word = kws[q];
        int i = (q << 6) + t;
        int kb = __popcll(word & ((1ull << t) - 1ull));
        bool kept = ((word >> t) & 1ull) != 0ull;
        int krank = run + kb;                // kept rows before i
        if (kept) {
            if (krank < OUTN) fi[krank] = i;
        } else if (i < TOPN) {
            int slot = snk + (i - krank);    // non-kept rank = i - kept_before
            if (slot < OUTN) fi[slot] = i;
        }
        run += __popcll(word);
    }
    __syncthreads();

    for (int q = t; q < OUTN; q += 64) {
        int r = fi[q];
        bool kv = q < snk;
        size_t ob = (size_t)img * TOPN + r;
        float sv = kv ? sc[ob] : 0.0f;
        int o = img * OUTN + q;
        out[o * 4 + 0] = bfr(bx[ob * 4 + 0]);
        out[o * 4 + 1] = bfr(bx[ob * 4 + 1]);
        out[o * 4 + 2] = bfr(bx[ob * 4 + 2]);
        out[o * 4 + 3] = bfr(bx[ob * 4 + 3]);
        out[6400 + o] = bfr(sv);
        out[8000 + o] = (float)cl[ob];
        out[9600 + o] = (sv > 0.0f) ? 1.0f : 0.0f;
    }
}

extern "C" void kernel_launch(void* const* d_in, const int* in_sizes, int n_in,
                              void* d_out, int out_size, void* d_ws, size_t ws_size,
                              hipStream_t stream) {
    const float* loc    = (const float*)d_in[0];
    const int*   levels = (const int*)d_in[1];
    const int*   batch  = (const int*)d_in[2];
    const float* cls    = (const float*)d_in[3];
    const float* breg   = (const float*)d_in[4];
    const float* ctr    = (const float*)d_in[5];
    const int*   imsz   = (const int*)d_in[6];

    char* ws = (char*)d_ws;
    unsigned long long* cand   = (unsigned long long*)(ws + 0);        // 524288
    unsigned*           ghist  = (unsigned*)(ws + 524288);             // 66560 used
    u64*                srt    = (u64*)(ws + 591872);                  // 128000 (carved from ghist slack, ends 719872)
    float*              bx     = (float*)(ws + 852096);                // 256000
    float*              bo     = (float*)(ws + 1108096);               // 256000
    float*              ar     = (float*)(ws + 1364096);               // 64000
    float*              sc     = (float*)(ws + 1428096);               // 64000
    int*                cl     = (int*)(ws + 1492096);                 // 64000
    unsigned*           k0     = (unsigned*)(ws + 1556096);            // 64000
    unsigned*           gcnt   = (unsigned*)(ws + 1620096);            // 1024 (16 imgs x 64B line)
    unsigned*           thrbuf = (unsigned*)(ws + 1621120);            // 128
    u64*                sup    = (u64*)(ws + 1703936);                 // 1114112 (end 2818048 = proven envelope)
    float* out = (float*)d_out;

    hipMemsetAsync(ghist, 0, 16 * NB2P * 4, stream);
    hipMemsetAsync(gcnt, 0, 1024, stream);
    hipMemsetAsync(srt, 0, 16 * TOPN * 8, stream);
    k_hist    <<<512,  1024, 0, stream>>>((const float4*)cls, ctr, batch, ghist);
    k_thresh  <<<16,   256,  0, stream>>>(ghist, thrbuf);
    k_collect <<<2048, 256,  0, stream>>>((const float4*)cls, ctr, batch, thrbuf, gcnt, cand);
    k_rank    <<<64,   1024, 0, stream>>>(cand, gcnt, srt);
    k_build   <<<16,   256,  0, stream>>>(srt, loc, breg, levels, imsz,
                                          bx, sc, cl, k0, bo, ar);
    k_iou     <<<256,  1024, 0, stream>>>(bo, ar, sup);
    k_scan_out<<<16,   64,   0, stream>>>(sup, k0, bx, sc, cl, out);
}

// Round 10
// 303.347 us; speedup vs baseline: 1.2730x; 1.0558x over previous
//
#include <hip/hip_runtime.h>
#include <math.h>

#pragma clang fp contract(off)

#define MPTS   2097152
#define NIMG   16
#define NCLS   11
#define CUTB   0x3F000000u   /* __float_as_uint(0.5f) — histogram floor */
#define PREB   0x3F4CCC00u   /* prerecord floor: just under bits(0.8) */
#define BSAFE  620           /* min threshold bin for list-mode safety */
#define PRECAP 14336         /* per-image prerecord capacity */
#define NB2    1026          /* bins covering s in [0.5, 1.0] (+guard) */
#define NB2P   1040          /* padded per-image stride */
#define MARG   96u
#define CAP    4096
#define TOPN   1000
#define OUTN   100
#define LCAP   64            /* per-block per-image LDS candidate slots */

typedef unsigned long long u64;

// triangular suppression-mask storage: per image, chunks c=0..15 (rows 64c..64c+63),
// each row stores words w=c..15 (j-words); chunk base in u64 words:
#define SUPW_PER_IMG 8704
__device__ __forceinline__ int chunk_base(int c) {
    return 64 * (16 * c - (c * (c - 1)) / 2);
}

// exact f32 sigmoid mirroring numpy: e = f32(exp64(-x)); 1/(1+e) in f32
__device__ inline float sigx(float x) {
    float e = (float)exp(-(double)x);
    return 1.0f / (1.0f + e);
}
// fast screen-only sigmoid (v_exp + v_rcp, ~2-3 ulp; margins are >=96 codes)
__device__ inline float sigf(float x) {
    float e = __expf(-x);
    return __builtin_amdgcn_rcpf(1.0f + e);
}
// round f32 -> bf16 (RNE) -> f32, to match the bf16-quantized reference
__device__ inline float bfr(float x) {
    unsigned u = __float_as_uint(x);
    unsigned r = (u + 0x7FFFu + ((u >> 16) & 1u)) & 0xFFFF0000u;
    return __uint_as_float(r);
}
// uniform-lane u64 broadcast via v_readlane (no LDS round trip)
__device__ __forceinline__ u64 rdlane64(u64 v, int l) {
    unsigned lo = (unsigned)__builtin_amdgcn_readlane((int)(unsigned)(v & 0xFFFFFFFFull), l);
    unsigned hi = (unsigned)__builtin_amdgcn_readlane((int)(unsigned)(v >> 32), l);
    return ((u64)hi << 32) | (u64)lo;
}

// ---- pass A: FAST histogram [0.5,1.0] + prerecord of fb>=bits(0.8) -----
// gcnt layout per image i (16-word / 64B line): word 0 = candidate count,
// word 8 = prerecord count. gcnt[1] (line 0, word 1) = unsafe-mode flag.
__global__ __launch_bounds__(1024)
void k_hist(const float4* __restrict__ cls4, const float* __restrict__ ctr,
            const int* __restrict__ batch, unsigned* __restrict__ ghist,
            unsigned* __restrict__ gcnt, unsigned* __restrict__ prerec) {
    __shared__ unsigned hist[NB2];
    __shared__ unsigned pA[512], pB[256];
    __shared__ unsigned cA, cB, bA;
    __shared__ int simg;
    const int F4  = MPTS * NCLS / 4;       // 5767168 float4s
    const int FPB = F4 / 512;              // 11264 per block
    int f0 = blockIdx.x * FPB;
    int t = threadIdx.x;
    for (int i = t; i < NB2; i += 1024) hist[i] = 0;
    if (t == 0) { simg = batch[(unsigned)(4u * (unsigned)f0) / NCLS]; cA = 0; cB = 0; }
    __syncthreads();
    int bi = simg;
    unsigned pc = 0xFFFFFFFFu;             // cached point
    float sfc = 0.0f;
    int bc = 0;
    for (int f = f0 + t; f < f0 + FPB; f += 1024) {
        float4 v = cls4[f];
        float va[4] = {v.x, v.y, v.z, v.w};
        unsigned e0 = 4u * (unsigned)f;
        #pragma unroll
        for (int j = 0; j < 4; j++) {
            float ck = va[j];
            if (ck <= 0.0f) continue;      // s <= 0.5: below histogram range
            unsigned e = e0 + (unsigned)j;
            unsigned p = e / NCLS;
            unsigned k = e - p * NCLS;
            if (k == 10u) continue;        // class 10 zeroed by ref
            if (p != pc) {
                pc = p; sfc = sigf(ctr[p]); bc = batch[p];
            }
            unsigned fb = __float_as_uint(sigf(ck) * sfc);
            if (fb < CUTB) continue;
            unsigned bin = (fb - CUTB) >> 13;
            if (bin >= NB2) bin = NB2 - 1;             // s==1.0 guard
            if (bc == bi) atomicAdd(&hist[bin], 1u);
            else          atomicAdd(&ghist[(size_t)bc * NB2P + bin], 1u);
            if (fb >= PREB) {              // prerecord for list-mode collect
                if (bc == bi) {
                    unsigned sl = atomicAdd(&cA, 1u);
                    if (sl < 512u) pA[sl] = e;
                    else {
                        unsigned pos = atomicAdd(&gcnt[bi * 16 + 8], 1u);
                        if (pos < PRECAP) prerec[(size_t)bi * PRECAP + pos] = e;
                    }
                } else {
                    unsigned sl = atomicAdd(&cB, 1u);
                    if (sl < 256u) pB[sl] = e;
                    else {
                        unsigned pos = atomicAdd(&gcnt[bc * 16 + 8], 1u);
                        if (pos < PRECAP) prerec[(size_t)bc * PRECAP + pos] = e;
                    }
                }
            }
        }
    }
    __syncthreads();
    unsigned* gh = ghist + (size_t)bi * NB2P;
    for (int i = t; i < NB2; i += 1024) {
        unsigned v2 = hist[i];
        if (v2) atomicAdd(&gh[i], v2);
    }
    if (t == 0) {
        unsigned nn = cA; if (nn > 512u) nn = 512u;
        cA = nn;
        bA = nn ? atomicAdd(&gcnt[bi * 16 + 8], nn) : 0u;
    }
    __syncthreads();
    for (unsigned i = t; i < cA; i += 1024) {
        unsigned pos = bA + i;
        if (pos < PRECAP) prerec[(size_t)bi * PRECAP + pos] = pA[i];
    }
    unsigned nb = cB; if (nb > 256u) nb = 256u;
    for (unsigned i = t; i < nb; i += 1024) {       // boundary spill (rare)
        unsigned e2 = pB[i];
        int img2 = batch[e2 / NCLS];
        unsigned pos = atomicAdd(&gcnt[img2 * 16 + 8], 1u);
        if (pos < PRECAP) prerec[(size_t)img2 * PRECAP + pos] = e2;
    }
}

// ---- threshold: largest bin B with fast-suffix-count >= TOPN -----------
// Also decides list-mode safety: B >= BSAFE guarantees every screen-passer
// (sf > scrc) has fast bits >= PREB, i.e. is prerecorded; pcnt <= PRECAP
// guarantees no prerecord was dropped. Violation -> gcnt[1] flag -> full scan.
__global__ void k_thresh(const unsigned* __restrict__ ghist, unsigned* __restrict__ thrbuf,
                         unsigned* __restrict__ gcnt) {
    int img = blockIdx.x;
    const unsigned* h = ghist + (size_t)img * NB2P;
    __shared__ unsigned psum[256];
    int t = threadIdx.x;
    unsigned s = 0;
    int base = t * 5;                      // 5 bins/thread, threads 0..205 cover 1026
    for (int i = 0; i < 5; i++) { int b = base + i; if (b < NB2) s += h[b]; }
    psum[t] = s;
    __syncthreads();
    if (t == 0) {
        unsigned run = 0; int B = 0;
        for (int u = 205; u >= 0; u--) {
            if (run + psum[u] >= (unsigned)TOPN) {
                int btop = u * 5 + 4; if (btop > NB2 - 1) btop = NB2 - 1;
                for (int b = btop; b >= u * 5; b--) {
                    run += h[b];
                    if (run >= (unsigned)TOPN) { B = b; break; }
                }
                break;
            }
            run += psum[u];
        }
        unsigned TB = CUTB + ((unsigned)B << 13) - MARG;   // fast->exact slack
        thrbuf[2 * img] = TB;
        thrbuf[2 * img + 1] = __float_as_uint(__uint_as_float(TB) * 0.998f); // screen
        if (B < BSAFE || gcnt[img * 16 + 8] > PRECAP) atomicOr(&gcnt[1], 1u);
    }
}

// ---- pass B: collect u64 keys ------------------------------------------
// List mode (safe): process only prerecorded elements (~150K) — provably
// the same candidate set as the full scan (every sf>scrc passer has
// fb>=PREB). Full mode (fallback): byte-identical round-9 scan.
__global__ __launch_bounds__(256)
void k_collect(const float4* __restrict__ cls4, const float* __restrict__ clsf,
               const float* __restrict__ ctr, const int* __restrict__ batch,
               const unsigned* __restrict__ thrbuf, unsigned* __restrict__ gcnt,
               const unsigned* __restrict__ prerec, unsigned long long* __restrict__ cand) {
    int t = threadIdx.x;
    if (gcnt[1] == 0u) {                   // ---- LIST MODE ----
        if (blockIdx.x >= 256) return;
        int img = blockIdx.x >> 4;
        int sub = blockIdx.x & 15;
        unsigned TB = thrbuf[2 * img];
        float scr = __uint_as_float(thrbuf[2 * img + 1]);
        unsigned n = gcnt[img * 16 + 8];   // <= PRECAP in safe mode
        __shared__ u64 l2[512];
        __shared__ unsigned c2, b2;
        if (t == 0) c2 = 0;
        __syncthreads();
        const unsigned* pr = prerec + (size_t)img * PRECAP;
        for (unsigned i = (unsigned)(sub * 256 + t); i < n; i += 4096) {
            unsigned e = pr[i];
            unsigned p = e / NCLS;
            float ck = clsf[e];
            float cgs = ctr[p];
            float sf = sigf(ck) * sigf(cgs);
            if (sf > scr) {
                float s = sigx(ck) * sigx(cgs);        // exact f32 chain
                unsigned bits = __float_as_uint(s);
                if (bits >= TB && s > 0.05f) {
                    u64 key = ((u64)bits << 32) | (u64)(0xFFFFFFFFu - e);
                    unsigned sl = atomicAdd(&c2, 1u);
                    if (sl < 512u) l2[sl] = key;
                    else {
                        unsigned pos = atomicAdd(&gcnt[img * 16], 1u);
                        if (pos < CAP) cand[(size_t)img * CAP + pos] = key;
                    }
                }
            }
        }
        __syncthreads();
        if (t == 0) {
            unsigned nn = c2; if (nn > 512u) nn = 512u;
            c2 = nn;
            b2 = nn ? atomicAdd(&gcnt[img * 16], nn) : 0u;
        }
        __syncthreads();
        for (unsigned sl = t; sl < c2; sl += 256) {
            unsigned pos = b2 + sl;
            if (pos < CAP) cand[(size_t)img * CAP + pos] = l2[sl];
        }
        return;
    }
    // ---- FULL MODE (fallback; identical to round-9 kernel) ----
    __shared__ unsigned sTB[NIMG];
    __shared__ float sSCR[NIMG];
    __shared__ u64 lbuf[NIMG][LCAP];
    __shared__ unsigned lcnt[NIMG];
    __shared__ unsigned lbase[NIMG];
    if (t < NIMG) {
        sTB[t]  = thrbuf[2 * t];
        sSCR[t] = __uint_as_float(thrbuf[2 * t + 1]);
        lcnt[t] = 0;
    }
    __syncthreads();
    const int F4  = MPTS * NCLS / 4;       // 5767168
    const int FPB = F4 / 2048;             // 2816 per block
    int f0 = blockIdx.x * FPB;
    unsigned pc = 0xFFFFFFFFu;
    float cgs = 0.0f, sfc = 0.0f, sxc = 0.0f, scrc = 0.0f;
    bool havex = false;
    int bc = 0; unsigned TBc = 0;
    for (int f = f0 + t; f < f0 + FPB; f += 256) {
        float4 v = cls4[f];
        float va[4] = {v.x, v.y, v.z, v.w};
        unsigned e0 = 4u * (unsigned)f;
        #pragma unroll
        for (int j = 0; j < 4; j++) {
            float ck = va[j];
            if (ck <= -0.001f) continue;   // cannot reach the exact gate
            unsigned e = e0 + (unsigned)j;
            unsigned p = e / NCLS;
            unsigned k = e - p * NCLS;
            if (k == 10u) continue;
            if (p != pc) {
                pc = p; cgs = ctr[p]; bc = batch[p];
                sfc = sigf(cgs); havex = false;
                TBc = sTB[bc]; scrc = sSCR[bc];
            }
            float sf = sigf(ck) * sfc;
            if (sf > scrc) {                           // rare screen pass
                if (!havex) { sxc = sigx(cgs); havex = true; }
                float s = sigx(ck) * sxc;              // exact f32 chain
                unsigned bits = __float_as_uint(s);
                if (bits >= TBc && s > 0.05f) {
                    u64 key = ((u64)bits << 32) | (u64)(0xFFFFFFFFu - e);
                    unsigned slot = atomicAdd(&lcnt[bc], 1u);
                    if (slot < LCAP) lbuf[bc][slot] = key;
                    else {                             // overflow fallback (exact)
                        unsigned pos = atomicAdd(&gcnt[bc * 16], 1u);
                        if (pos < CAP) cand[(size_t)bc * CAP + pos] = key;
                    }
                }
            }
        }
    }
    __syncthreads();
    if (t < NIMG) {
        unsigned n = lcnt[t]; if (n > LCAP) n = LCAP;
        lcnt[t] = n;
        lbase[t] = n ? atomicAdd(&gcnt[t * 16], n) : 0u;
    }
    __syncthreads();
    for (int s = t; s < NIMG * LCAP; s += 256) {
        int im = s >> 6;                   // LCAP == 64
        int sl = s & (LCAP - 1);
        if (sl < (int)lcnt[im]) {
            unsigned pos = lbase[im] + (unsigned)sl;
            if (pos < CAP) cand[(size_t)im * CAP + pos] = lbuf[im][sl];
        }
    }
}

// ---- fused rank-select + f32 box build (bit-exact np f32 op order) -----
// Rank: keys unique -> position = #{j: key_j > key_i} (barrier-free count).
// Ranked list lives in LDS (zero-padded = old srt semantics). Build phase
// math identical to round-9 k_build; fmax reductions are rounding-free so
// the wider stride is exact.
__global__ __launch_bounds__(1024)
void k_rankb(const u64* __restrict__ cand, const unsigned* __restrict__ gcnt,
             const float* __restrict__ loc, const float* __restrict__ breg,
             const int* __restrict__ levels, const int* __restrict__ imsz,
             float* __restrict__ bx, float* __restrict__ sc, int* __restrict__ cl,
             unsigned* __restrict__ k0, float* __restrict__ bo, float* __restrict__ ar) {
    int img = blockIdx.x;
    int t = threadIdx.x;
    __shared__ u64 keys[CAP];
    __shared__ u64 srtl[TOPN];
    __shared__ float red[1024];
    __shared__ float smc;
    unsigned n = gcnt[img * 16]; if (n > CAP) n = CAP;
    for (int i = t; i < (int)n; i += 1024) keys[i] = cand[(size_t)img * CAP + i];
    for (int i = t; i < TOPN; i += 1024) srtl[i] = 0ull;
    __syncthreads();
    for (int ii = t; ii < (int)n; ii += 1024) {
        u64 me = keys[ii];
        int rank = 0;
        int j = 0;
        for (; j + 4 <= (int)n; j += 4) {   // wave-broadcast LDS reads
            rank += (keys[j]     > me);
            rank += (keys[j + 1] > me);
            rank += (keys[j + 2] > me);
            rank += (keys[j + 3] > me);
        }
        for (; j < (int)n; j++) rank += (keys[j] > me);
        if (rank < TOPN) srtl[rank] = me;
    }
    __syncthreads();
    float wmax = (float)imsz[img * 2 + 1] - 1.0f;   // hw = [h, w] -> w-1
    float hmax = (float)imsz[img * 2 + 0] - 1.0f;
    float lmax = 0.0f;
    for (int r = t; r < TOPN; r += 1024) {
        u64 kv = srtl[r];
        unsigned bits = (unsigned)(kv >> 32);
        unsigned idx = 0xFFFFFFFFu - (unsigned)(kv & 0xFFFFFFFFull);
        float v = __uint_as_float(bits);
        bool v0 = (kv != 0ull) && (v > 0.0f);
        if (!v0) idx = 0;
        unsigned pt = idx / NCLS;
        int c = (int)(idx - pt * NCLS);
        float lx = loc[(size_t)pt * 2 + 0], ly = loc[(size_t)pt * 2 + 1];
        float st = (float)(8 << levels[pt]);        // 8..128, pow2 -> exact scaling
        float r0 = breg[(size_t)pt * 4 + 0] * st;
        float r1 = breg[(size_t)pt * 4 + 1] * st;
        float r2 = breg[(size_t)pt * 4 + 2] * st;
        float r3 = breg[(size_t)pt * 4 + 3] * st;
        float x1 = lx - r0, y1 = ly - r1, x2 = lx + r2, y2 = ly + r3;
        x1 = fminf(fmaxf(x1, 0.0f), wmax);
        y1 = fminf(fmaxf(y1, 0.0f), hmax);
        x2 = fminf(fmaxf(x2, 0.0f), wmax);
        y2 = fminf(fmaxf(y2, 0.0f), hmax);
        float wss = (x2 - x1) + 1.0f, hss = (y2 - y1) + 1.0f;
        bool keep = v0 && (wss >= 0.0f) && (hss >= 0.0f);
        size_t ob = (size_t)img * TOPN + r;
        bx[ob * 4 + 0] = x1; bx[ob * 4 + 1] = y1;
        bx[ob * 4 + 2] = x2; bx[ob * 4 + 3] = y2;
        sc[ob] = v0 ? sqrtf(v) : 0.0f;
        cl[ob] = c + 1;
        k0[ob] = keep ? 1u : 0u;
        if (keep) lmax = fmaxf(lmax, fmaxf(fmaxf(x1, y1), fmaxf(x2, y2)));
    }
    red[t] = lmax; __syncthreads();
    for (int sft = 512; sft > 0; sft >>= 1) {
        if (t < sft) red[t] = fmaxf(red[t], red[t + sft]);
        __syncthreads();
    }
    if (t == 0) smc = red[0];
    __syncthreads();
    float off1 = smc + 1.0f;                        // max_coord + 1.0 (f32)
    for (int r = t; r < TOPN; r += 1024) {
        size_t ob = (size_t)img * TOPN + r;
        float o = (float)cl[ob] * off1;             // cl.astype(f32) * (mc+1)
        float x1 = bx[ob * 4 + 0] + o, y1 = bx[ob * 4 + 1] + o;
        float x2 = bx[ob * 4 + 2] + o, y2 = bx[ob * 4 + 3] + o;
        bo[ob * 4 + 0] = x1; bo[ob * 4 + 1] = y1;
        bo[ob * 4 + 2] = x2; bo[ob * 4 + 3] = y2;
        float aw = fmaxf((x2 - x1) + 1.0f, 0.0f);   // clip(x2-x1+1, 0)
        float ah = fmaxf((y2 - y1) + 1.0f, 0.0f);
        ar[ob] = aw * ah;
    }
}

// ---- IoU suppression bitmask, strictly-upper triangle ------------------
__global__ __launch_bounds__(1024)
void k_iou(const float* __restrict__ bo, const float* __restrict__ ar,
           u64* __restrict__ sup) {
    int img = blockIdx.x >> 4;
    int c   = blockIdx.x & 15;
    __shared__ float sx1[1024], sy1[1024], sx2[1024], sy2[1024], sa[1024];
    int tid = threadIdx.x;
    {
        int i = tid;
        if (i < TOPN) {
            size_t ob = (size_t)img * TOPN + i;
            sx1[i] = bo[ob * 4 + 0]; sy1[i] = bo[ob * 4 + 1];
            sx2[i] = bo[ob * 4 + 2]; sy2[i] = bo[ob * 4 + 3];
            sa[i]  = ar[ob];
        } else {
            sx1[i] = 0.0f; sy1[i] = 0.0f; sx2[i] = 0.0f; sy2[i] = 0.0f; sa[i] = 0.0f;
        }
    }
    __syncthreads();
    int width = 16 - c;
    int items = 64 * width;
    u64* supc = sup + (size_t)img * SUPW_PER_IMG + chunk_base(c);
    for (int it = tid; it < items; it += 1024) {
        int r  = it & 63;
        int wq = c + (it >> 6);
        int i  = c * 64 + r;
        if (i >= TOPN) continue;
        float x1 = sx1[i], y1 = sy1[i], x2 = sx2[i], y2 = sy2[i], a = sa[i];
        int j0 = wq * 64;
        u64 m = 0ull;
        #pragma unroll 8
        for (int jj = 0; jj < 64; jj++) {
            int j = j0 + jj;
            float xx1 = fmaxf(x1, sx1[j]);
            float yy1 = fmaxf(y1, sy1[j]);
            float xx2 = fminf(x2, sx2[j]);
            float yy2 = fminf(y2, sy2[j]);
            float iw = fmaxf((xx2 - xx1) + 1.0f, 0.0f);
            float ih = fmaxf((yy2 - yy1) + 1.0f, 0.0f);
            float inter = iw * ih;
            float den = fmaxf((a + sa[j]) - inter, 1e-9f);  // ref assoc order
            if (inter / den > 0.6f) m |= (1ull << jj);
        }
        u64 vm = ~0ull;
        if (wq == c) vm = (r >= 63) ? 0ull : (~0ull << (r + 1));   // j > i
        int rem = TOPN - j0;                                        // j < TOPN
        if (rem < 64) vm &= (rem <= 0) ? 0ull : ((1ull << rem) - 1ull);
        supc[(size_t)r * width + (wq - c)] = m & vm;
    }
}

// ---- NMS scan helpers (sparse diagonal + distributed keep-vector) ------
__device__ __forceinline__ void scan_pref(const u64* __restrict__ supi, int rg, int w, int t,
                                          int C, u64 (&V)[16], u64 &anyV, u64 &dmy) {
    int wd = 16 - C;
    const u64* rb = supi + chunk_base(C) + (rg << 4) * wd - C + w;
    u64 a = 0ull;
    #pragma unroll
    for (int i = 0; i < 16; i++) {
        u64 x = rb[i * wd];                 // in-bounds even when w<C (masked)
        V[i] = (w >= C) ? x : 0ull;
        a |= V[i];
    }
    anyV = a;
    dmy = supi[chunk_base(C) + (size_t)t * wd];   // word C of row t (diagonal)
}

__device__ __forceinline__ void scan_step(int rg, int w, int C,
                                          u64 (&V)[16], u64 anyV, u64 dmy,
                                          u64 &kw_local) {
    u64 m = rdlane64(kw_local, C);            // word C (lane C: rg=0,w=C)
    u64 act = __ballot(dmy != 0ull) & m;
    while (act) {
        int r = __builtin_ctzll(act);
        u64 d = rdlane64(dmy, r);
        m &= ~d;                              // diag has only j>r bits
        act &= act - 1ull;
        act &= m;                             // drop rows suppressed by r
    }
    if (__ballot(anyV != 0ull)) {
        u64 loc = 0ull;
        #pragma unroll
        for (int i = 0; i < 16; i++) {
            int row = (rg << 4) + i;
            loc |= V[i] & ((u64)0 - ((m >> row) & 1ull));
        }
        u64 t1 = loc | __shfl_xor(loc, 16);
        u64 t2 = t1 | __shfl_xor(t1, 32);     // word-w OR over all 64 rows
        kw_local = ((w == C) ? m : kw_local) & ~t2;  // t2==0 for w<C
    } else if (w == C) {
        kw_local = m;
    }
}

// ---- single-wave sparse bitmask scan + wave-parallel output ------------
__global__ __launch_bounds__(64)
void k_scan_out(const u64* __restrict__ sup, const unsigned* __restrict__ k0,
                const float* __restrict__ bx, const float* __restrict__ sc,
                const int* __restrict__ cl, float* __restrict__ out) {
    int img = blockIdx.x;
    int t = threadIdx.x;
    int rg = t >> 4, w = t & 15;
    const u64* supi = sup + (size_t)img * SUPW_PER_IMG;

    // distributed keep words: lane L holds word L&15 (replicated across rg)
    u64 kw_local = 0ull;
    #pragma unroll
    for (int q = 0; q < 16; q++) {
        int i = (q << 6) + t;
        unsigned vv = (i < TOPN) ? k0[(size_t)img * TOPN + i] : 0u;
        u64 bal = __ballot(vv != 0u);
        if (w == q) kw_local = bal;
    }

    u64 vA[16], vB[16], anyA, anyB, dA, dB;
    scan_pref(supi, rg, w, t, 0, vA, anyA, dA);
    for (int c = 0; c < 16; c += 2) {
        scan_pref(supi, rg, w, t, c + 1, vB, anyB, dB);  // flies under STEP(A)
        scan_step(rg, w, c, vA, anyA, dA, kw_local);
        if (c + 2 < 16) scan_pref(supi, rg, w, t, c + 2, vA, anyA, dA);
        scan_step(rg, w, c + 1, vB, anyB, dB, kw_local);
    }

    // replicated copy for the fill (literal-lane readlanes)
    u64 kws[16];
    #pragma unroll
    for (int q = 0; q < 16; q++) kws[q] = rdlane64(kw_local, q);

    // wave-parallel stable fill via popcount ranks (kept first, then rest)
    __shared__ int fi[OUTN];
    int total_k = 0;
    #pragma unroll
    for (int q = 0; q < 16; q++) total_k += __popcll(kws[q]);
    int snk = total_k < OUTN ? total_k : OUTN;
    int run = 0;
    #pragma unroll
    for (int q = 0; q < 16; q++) {
        u64 word = kws[q];
        int i = (q << 6) + t;
        int kb = __popcll(word & ((1ull << t) - 1ull));
        bool kept = ((word >> t) & 1ull) != 0ull;
        int krank = run + kb;                // kept rows before i
        if (kept) {
            if (krank < OUTN) fi[krank] = i;
        } else if (i < TOPN) {
            int slot = snk + (i - krank);    // non-kept rank = i - kept_before
            if (slot < OUTN) fi[slot] = i;
        }
        run += __popcll(word);
    }
    __syncthreads();

    for (int q = t; q < OUTN; q += 64) {
        int r = fi[q];
        bool kv = q < snk;
        size_t ob = (size_t)img * TOPN + r;
        float sv = kv ? sc[ob] : 0.0f;
        int o = img * OUTN + q;
        out[o * 4 + 0] = bfr(bx[ob * 4 + 0]);
        out[o * 4 + 1] = bfr(bx[ob * 4 + 1]);
        out[o * 4 + 2] = bfr(bx[ob * 4 + 2]);
        out[o * 4 + 3] = bfr(bx[ob * 4 + 3]);
        out[6400 + o] = bfr(sv);
        out[8000 + o] = (float)cl[ob];
        out[9600 + o] = (sv > 0.0f) ? 1.0f : 0.0f;
    }
}

extern "C" void kernel_launch(void* const* d_in, const int* in_sizes, int n_in,
                              void* d_out, int out_size, void* d_ws, size_t ws_size,
                              hipStream_t stream) {
    const float* loc    = (const float*)d_in[0];
    const int*   levels = (const int*)d_in[1];
    const int*   batch  = (const int*)d_in[2];
    const float* cls    = (const float*)d_in[3];
    const float* breg   = (const float*)d_in[4];
    const float* ctr    = (const float*)d_in[5];
    const int*   imsz   = (const int*)d_in[6];

    char* ws = (char*)d_ws;
    unsigned long long* cand   = (unsigned long long*)(ws + 0);        // 524288
    unsigned*           ghist  = (unsigned*)(ws + 524288);             // 66560 used
    float*              bx     = (float*)(ws + 852096);                // 256000
    float*              bo     = (float*)(ws + 1108096);               // 256000
    float*              ar     = (float*)(ws + 1364096);               // 64000
    float*              sc     = (float*)(ws + 1428096);               // 64000
    int*                cl     = (int*)(ws + 1492096);                 // 64000
    unsigned*           k0     = (unsigned*)(ws + 1556096);            // 64000
    unsigned*           gcnt   = (unsigned*)(ws + 1620096);            // 1024 (16 imgs x 64B line; [1]=flag, +8=pcnt)
    unsigned*           thrbuf = (unsigned*)(ws + 1621120);            // 128
    u64*                sup    = (u64*)(ws + 1703936);                 // 1114112 (end 2818048 = proven envelope)
    unsigned*           prerec = (unsigned*)(ws + 1703936);            // aliases sup: 16*14336*4 = 917504
                                                                       // (prerec consumed by k_collect BEFORE k_iou writes sup)
    float* out = (float*)d_out;

    hipMemsetAsync(ghist, 0, 16 * NB2P * 4, stream);
    hipMemsetAsync(gcnt, 0, 1024, stream);
    k_hist    <<<512,  1024, 0, stream>>>((const float4*)cls, ctr, batch, ghist, gcnt, prerec);
    k_thresh  <<<16,   256,  0, stream>>>(ghist, thrbuf, gcnt);
    k_collect <<<2048, 256,  0, stream>>>((const float4*)cls, cls, ctr, batch, thrbuf, gcnt, prerec, cand);
    k_rankb   <<<16,   1024, 0, stream>>>(cand, gcnt, loc, breg, levels, imsz,
                                          bx, sc, cl, k0, bo, ar);
    k_iou     <<<256,  1024, 0, stream>>>(bo, ar, sup);
    k_scan_out<<<16,   64,   0, stream>>>(sup, k0, bx, sc, cl, out);
}